// Round 8
// baseline (395.667 us; speedup 1.0000x reference)
//
#include <hip/hip_runtime.h>
#include <cmath>

// ---------------------------------------------------------------------------
// Problem constants: B=16, N=196, D=512, M=20, H=8, hd=64, k=51
//   tokens = 3136, 3D = 1536
// ---------------------------------------------------------------------------

typedef __attribute__((ext_vector_type(8))) short bf16x8v;
typedef __attribute__((ext_vector_type(4))) float f32x4v;

__device__ __forceinline__ unsigned short f2bf_rne(float x) {
  unsigned u = __float_as_uint(x);
  u += 0x7fffu + ((u >> 16) & 1u);   // round-to-nearest-even
  return (unsigned short)(u >> 16);
}
__device__ __forceinline__ float bf2f(unsigned short h) {
  return __uint_as_float(((unsigned)h) << 16);
}

__device__ __forceinline__ void split3_8(const float* xs,
    bf16x8v& o0, bf16x8v& o1, bf16x8v& o2) {
#pragma unroll
  for (int e = 0; e < 8; e++) {
    float x = xs[e];
    unsigned short s0 = f2bf_rne(x); float r1 = x - bf2f(s0);
    unsigned short s1 = f2bf_rne(r1); float r2 = r1 - bf2f(s1);
    unsigned short s2 = f2bf_rne(r2);
    o0[e] = (short)s0; o1[e] = (short)s1; o2[e] = (short)s2;
  }
}

// ---------------------------------------------------------------------------
// split2: X -> 3 bf16 limb planes (plane stride = n elements). Handles two
// tensors per launch (fewer kernel launches). n0, n1 multiples of 2048.
// ---------------------------------------------------------------------------
__global__ __launch_bounds__(256) void split2_kernel(
    const float* __restrict__ X0, unsigned short* __restrict__ O0, int n0,
    const float* __restrict__ X1, unsigned short* __restrict__ O1, int n1)
{
  int nb0 = n0 >> 11;
  const float* X; unsigned short* O; long long i8, n;
  if ((int)blockIdx.x < nb0) {
    X = X0; O = O0; n = n0; i8 = (long long)blockIdx.x * 256 + threadIdx.x;
  } else {
    X = X1; O = O1; n = n1; i8 = (long long)(blockIdx.x - nb0) * 256 + threadIdx.x;
  }
  const float4 aa = *(const float4*)(X + i8 * 8);
  const float4 bb = *(const float4*)(X + i8 * 8 + 4);
  float xs[8] = {aa.x, aa.y, aa.z, aa.w, bb.x, bb.y, bb.z, bb.w};
  bf16x8v o0, o1, o2;
  split3_8(xs, o0, o1, o2);
  *(bf16x8v*)(O + i8 * 8)          = o0;
  *(bf16x8v*)(O + n + i8 * 8)      = o1;
  *(bf16x8v*)(O + 2 * n + i8 * 8)  = o2;
}

#define GBK 32
#define AROWB 80                 // LDS bytes per row (32 bf16 + 16B pad)
#define SPLIT_SZ (128 * AROWB)   // 10240 B per limb plane
#define BBASE (3 * SPLIT_SZ)     // B tile base: 30720

// ---------------------------------------------------------------------------
// Pre-split bf16x3 MFMA GEMM: C[i,j] = sum_k A[i,k]*B[j,k] (+bias[j])
// (+res[i,j]). As/Bs are 3-plane bf16 limb tensors (row stride 512, plane
// stride aPlane/bPlane elements). K=512 fixed. N%128==0 required; M guarded.
// Staging is pure 16B copies (no per-tile split VALU work).
// ---------------------------------------------------------------------------
__global__ __launch_bounds__(256) void gemm_ps3_kernel(
    const unsigned short* __restrict__ As, const unsigned short* __restrict__ Bs,
    float* __restrict__ C, const float* __restrict__ bias,
    const float* __restrict__ res,
    int M, int N, int ldc, long long aPlane, long long bPlane)
{
  __shared__ __align__(16) unsigned char smem[2 * BBASE];  // 61440 B

  int tid = threadIdx.x;
  int lane = tid & 63, w = tid >> 6;
  int wrow = w >> 1, wcol = w & 1;
  int i0 = blockIdx.x * 128, j0 = blockIdx.y * 128;

  int r = tid >> 1, hh = tid & 1;
  int arow = i0 + r; if (arow > M - 1) arow = M - 1;
  int brow = j0 + r; if (brow > N - 1) brow = N - 1;
  const unsigned short* ap = As + (size_t)arow * 512 + hh * 16;
  const unsigned short* bp = Bs + (size_t)brow * 512 + hh * 16;
  unsigned swoff = (unsigned)r * AROWB + (unsigned)hh * 32;

  f32x4v acc[4][4];
#pragma unroll
  for (int fi = 0; fi < 4; fi++)
#pragma unroll
    for (int fj = 0; fj < 4; fj++) acc[fi][fj] = (f32x4v){0.f, 0.f, 0.f, 0.f};

  unsigned fr_a = (unsigned)(wrow * 64 + (lane & 15)) * AROWB + (unsigned)(lane >> 4) * 16;
  unsigned fr_b = (unsigned)(wcol * 64 + (lane & 15)) * AROWB + (unsigned)(lane >> 4) * 16 + BBASE;

  for (int k0 = 0; k0 < 512; k0 += GBK) {
    bf16x8v a0[3], a1[3], b0v[3], b1v[3];
#pragma unroll
    for (int s = 0; s < 3; s++) {
      a0[s]  = *(const bf16x8v*)(ap + s * aPlane + k0);
      a1[s]  = *(const bf16x8v*)(ap + s * aPlane + k0 + 8);
      b0v[s] = *(const bf16x8v*)(bp + s * bPlane + k0);
      b1v[s] = *(const bf16x8v*)(bp + s * bPlane + k0 + 8);
    }
    __syncthreads();  // previous chunk's frag reads complete
#pragma unroll
    for (int s = 0; s < 3; s++) {
      *(bf16x8v*)(smem + s * SPLIT_SZ + swoff)              = a0[s];
      *(bf16x8v*)(smem + s * SPLIT_SZ + swoff + 16)         = a1[s];
      *(bf16x8v*)(smem + BBASE + s * SPLIT_SZ + swoff)      = b0v[s];
      *(bf16x8v*)(smem + BBASE + s * SPLIT_SZ + swoff + 16) = b1v[s];
    }
    __syncthreads();

    bf16x8v af[4][3];
#pragma unroll
    for (int fi = 0; fi < 4; fi++)
#pragma unroll
      for (int s = 0; s < 3; s++)
        af[fi][s] = *(const bf16x8v*)(smem + s * SPLIT_SZ + fr_a + fi * (16 * AROWB));

#pragma unroll
    for (int fj = 0; fj < 4; fj++) {
      bf16x8v b0 = *(const bf16x8v*)(smem + 0 * SPLIT_SZ + fr_b + fj * (16 * AROWB));
      bf16x8v b1 = *(const bf16x8v*)(smem + 1 * SPLIT_SZ + fr_b + fj * (16 * AROWB));
      bf16x8v b2 = *(const bf16x8v*)(smem + 2 * SPLIT_SZ + fr_b + fj * (16 * AROWB));
#pragma unroll
      for (int fi = 0; fi < 4; fi++) {
        f32x4v c = acc[fi][fj];
        c = __builtin_amdgcn_mfma_f32_16x16x32_bf16(af[fi][2], b0, c, 0, 0, 0);
        c = __builtin_amdgcn_mfma_f32_16x16x32_bf16(af[fi][1], b1, c, 0, 0, 0);
        c = __builtin_amdgcn_mfma_f32_16x16x32_bf16(af[fi][0], b2, c, 0, 0, 0);
        c = __builtin_amdgcn_mfma_f32_16x16x32_bf16(af[fi][1], b0, c, 0, 0, 0);
        c = __builtin_amdgcn_mfma_f32_16x16x32_bf16(af[fi][0], b1, c, 0, 0, 0);
        c = __builtin_amdgcn_mfma_f32_16x16x32_bf16(af[fi][0], b0, c, 0, 0, 0);
        acc[fi][fj] = c;
      }
    }
  }

#pragma unroll
  for (int fi = 0; fi < 4; fi++) {
    int row0 = i0 + wrow * 64 + fi * 16 + (lane >> 4) * 4;
#pragma unroll
    for (int fj = 0; fj < 4; fj++) {
      int col = j0 + wcol * 64 + fj * 16 + (lane & 15);
      if (col >= N) continue;
      float badd = bias ? bias[col] : 0.0f;
      f32x4v v = acc[fi][fj];
#pragma unroll
      for (int rr = 0; rr < 4; rr++) {
        int row = row0 + rr;
        if (row < M) {
          float o = v[rr] + badd;
          if (res) o += res[(size_t)row * ldc + col];
          C[(size_t)row * ldc + col] = o;
        }
      }
    }
  }
}

// ---------------------------------------------------------------------------
// On-the-fly bf16x3 MFMA GEMM (kept verbatim for the batched attention GEMMs:
// strided A/B with z-batching, K over-read with zero-padded B rows).
// ---------------------------------------------------------------------------
__global__ __launch_bounds__(256) void gemm_bf16x3_kernel(
    const float* __restrict__ A, const float* __restrict__ B,
    float* __restrict__ C, const float* __restrict__ bias,
    const float* __restrict__ res,
    int M, int N, int K, int lda, int ldb, int ldc,
    int zInner, long long aOuter, long long aInner,
    long long bOuter, long long bInner,
    long long cOuter, long long cInner)
{
  int z = blockIdx.z;
  int zo = z / zInner, zi = z % zInner;
  A += zo * aOuter + zi * aInner;
  B += zo * bOuter + zi * bInner;
  C += zo * cOuter + zi * cInner;

  __shared__ __align__(16) unsigned char smem[2 * BBASE];  // 61440 B

  int tid = threadIdx.x;
  int lane = tid & 63, w = tid >> 6;
  int wrow = w >> 1, wcol = w & 1;
  int i0 = blockIdx.x * 128, j0 = blockIdx.y * 128;

  int srow = tid >> 1;
  int skh  = tid & 1;
  int arow = i0 + srow; if (arow > M - 1) arow = M - 1;
  int brow = j0 + srow; if (brow > N - 1) brow = N - 1;
  const float* aptr = A + (size_t)arow * lda + skh * 16;
  const float* bptr = B + (size_t)brow * ldb + skh * 16;
  unsigned swoff = (unsigned)srow * AROWB + (unsigned)skh * 32;

  f32x4v acc[4][4];
#pragma unroll
  for (int fi = 0; fi < 4; fi++)
#pragma unroll
    for (int fj = 0; fj < 4; fj++) acc[fi][fj] = (f32x4v){0.f, 0.f, 0.f, 0.f};

  unsigned fr_a = (unsigned)(wrow * 64 + (lane & 15)) * AROWB + (unsigned)(lane >> 4) * 16;
  unsigned fr_b = (unsigned)(wcol * 64 + (lane & 15)) * AROWB + (unsigned)(lane >> 4) * 16 + BBASE;

  for (int k0 = 0; k0 < K; k0 += GBK) {
    float av[16], bv[16];
    {
      const float4 q0 = *(const float4*)(aptr + k0);
      const float4 q1 = *(const float4*)(aptr + k0 + 4);
      const float4 q2 = *(const float4*)(aptr + k0 + 8);
      const float4 q3 = *(const float4*)(aptr + k0 + 12);
      av[0]=q0.x; av[1]=q0.y; av[2]=q0.z; av[3]=q0.w;
      av[4]=q1.x; av[5]=q1.y; av[6]=q1.z; av[7]=q1.w;
      av[8]=q2.x; av[9]=q2.y; av[10]=q2.z; av[11]=q2.w;
      av[12]=q3.x; av[13]=q3.y; av[14]=q3.z; av[15]=q3.w;
      const float4 r0 = *(const float4*)(bptr + k0);
      const float4 r1 = *(const float4*)(bptr + k0 + 4);
      const float4 r2 = *(const float4*)(bptr + k0 + 8);
      const float4 r3 = *(const float4*)(bptr + k0 + 12);
      bv[0]=r0.x; bv[1]=r0.y; bv[2]=r0.z; bv[3]=r0.w;
      bv[4]=r1.x; bv[5]=r1.y; bv[6]=r1.z; bv[7]=r1.w;
      bv[8]=r2.x; bv[9]=r2.y; bv[10]=r2.z; bv[11]=r2.w;
      bv[12]=r3.x; bv[13]=r3.y; bv[14]=r3.z; bv[15]=r3.w;
    }
    unsigned short ha[3][16], hb[3][16];
#pragma unroll
    for (int e = 0; e < 16; e++) {
      float x = av[e];
      unsigned short s0 = f2bf_rne(x); float r = x - bf2f(s0);
      unsigned short s1 = f2bf_rne(r); float r2 = r - bf2f(s1);
      unsigned short s2 = f2bf_rne(r2);
      ha[0][e] = s0; ha[1][e] = s1; ha[2][e] = s2;
      float y = bv[e];
      unsigned short t0 = f2bf_rne(y); float u = y - bf2f(t0);
      unsigned short t1 = f2bf_rne(u); float u2 = u - bf2f(t1);
      unsigned short t2 = f2bf_rne(u2);
      hb[0][e] = t0; hb[1][e] = t1; hb[2][e] = t2;
    }
    __syncthreads();
#pragma unroll
    for (int s = 0; s < 3; s++) {
      bf16x8v v0, v1, w0, w1;
#pragma unroll
      for (int e = 0; e < 8; e++) {
        v0[e] = (short)ha[s][e]; v1[e] = (short)ha[s][8 + e];
        w0[e] = (short)hb[s][e]; w1[e] = (short)hb[s][8 + e];
      }
      *(bf16x8v*)(smem + s * SPLIT_SZ + swoff)              = v0;
      *(bf16x8v*)(smem + s * SPLIT_SZ + swoff + 16)         = v1;
      *(bf16x8v*)(smem + BBASE + s * SPLIT_SZ + swoff)      = w0;
      *(bf16x8v*)(smem + BBASE + s * SPLIT_SZ + swoff + 16) = w1;
    }
    __syncthreads();

    bf16x8v af[4][3];
#pragma unroll
    for (int fi = 0; fi < 4; fi++)
#pragma unroll
      for (int s = 0; s < 3; s++)
        af[fi][s] = *(const bf16x8v*)(smem + s * SPLIT_SZ + fr_a + fi * (16 * AROWB));

#pragma unroll
    for (int fj = 0; fj < 4; fj++) {
      bf16x8v b0 = *(const bf16x8v*)(smem + 0 * SPLIT_SZ + fr_b + fj * (16 * AROWB));
      bf16x8v b1 = *(const bf16x8v*)(smem + 1 * SPLIT_SZ + fr_b + fj * (16 * AROWB));
      bf16x8v b2 = *(const bf16x8v*)(smem + 2 * SPLIT_SZ + fr_b + fj * (16 * AROWB));
#pragma unroll
      for (int fi = 0; fi < 4; fi++) {
        f32x4v c = acc[fi][fj];
        c = __builtin_amdgcn_mfma_f32_16x16x32_bf16(af[fi][2], b0, c, 0, 0, 0);
        c = __builtin_amdgcn_mfma_f32_16x16x32_bf16(af[fi][1], b1, c, 0, 0, 0);
        c = __builtin_amdgcn_mfma_f32_16x16x32_bf16(af[fi][0], b2, c, 0, 0, 0);
        c = __builtin_amdgcn_mfma_f32_16x16x32_bf16(af[fi][1], b0, c, 0, 0, 0);
        c = __builtin_amdgcn_mfma_f32_16x16x32_bf16(af[fi][0], b1, c, 0, 0, 0);
        c = __builtin_amdgcn_mfma_f32_16x16x32_bf16(af[fi][0], b0, c, 0, 0, 0);
        acc[fi][fj] = c;
      }
    }
  }

#pragma unroll
  for (int fi = 0; fi < 4; fi++) {
    int row0 = i0 + wrow * 64 + fi * 16 + (lane >> 4) * 4;
#pragma unroll
    for (int fj = 0; fj < 4; fj++) {
      int col = j0 + wcol * 64 + fj * 16 + (lane & 15);
      if (col >= N) continue;
      float badd = bias ? bias[col] : 0.0f;
      f32x4v v = acc[fi][fj];
#pragma unroll
      for (int rr = 0; rr < 4; rr++) {
        int row = row0 + rr;
        if (row < M) {
          float o = v[rr] + badd;
          if (res) o += res[(size_t)row * ldc + col];
          C[(size_t)row * ldc + col] = o;
        }
      }
    }
  }
}

// ---------------------------------------------------------------------------
// V transpose: per z=(b*8+h), Vt[z][d=64][kk=224] = V[kk][d] (kk>=196 -> 0).
// ---------------------------------------------------------------------------
__global__ __launch_bounds__(256) void vtrans_kernel(
    const float* __restrict__ qkv, float* __restrict__ Vt)
{
  __shared__ float lds[224 * 65];
  int z = blockIdx.x;
  int b = z >> 3, h = z & 7;
  int tid = threadIdx.x;
  const float* src = qkv + ((size_t)b * 196) * 1536 + 1024 + h * 64;
  for (int idx = tid; idx < 224 * 64; idx += 256) {
    int kk = idx >> 6, d = idx & 63;
    lds[kk * 65 + d] = (kk < 196) ? src[(size_t)kk * 1536 + d] : 0.0f;
  }
  __syncthreads();
  float* dst = Vt + (size_t)z * (64 * 224);
  for (int idx = tid; idx < 64 * 224; idx += 256) {
    int d = idx / 224, kk = idx - d * 224;
    dst[idx] = lds[kk * 65 + d];
  }
}

// In-place row softmax of scaled scores: rows of length 196, scale 1/sqrt(64).
__global__ __launch_bounds__(256) void softmax_kernel(float* __restrict__ S)
{
  int row = blockIdx.x * 4 + (threadIdx.x >> 6);
  int lane = threadIdx.x & 63;
  float* sr = S + (size_t)row * 196;
  double v[4];
#pragma unroll
  for (int t = 0; t < 4; t++) {
    int j = lane + 64 * t;
    v[t] = (j < 196) ? (double)sr[j] * 0.125 : -1e300;
  }
  double mx = fmax(fmax(v[0], v[1]), fmax(v[2], v[3]));
#pragma unroll
  for (int off = 1; off < 64; off <<= 1) mx = fmax(mx, __shfl_xor(mx, off));
  double e[4]; double s = 0.0;
#pragma unroll
  for (int t = 0; t < 4; t++) {
    int j = lane + 64 * t;
    e[t] = (j < 196) ? exp(v[t] - mx) : 0.0;
    s += e[t];
  }
#pragma unroll
  for (int off = 1; off < 64; off <<= 1) s += __shfl_xor(s, off);
  double inv = 1.0 / s;
#pragma unroll
  for (int t = 0; t < 4; t++) {
    int j = lane + 64 * t;
    if (j < 196) sr[j] = (float)(e[t] * inv);
  }
}

// In-place LayerNorm (ddof=0, eps=1e-5) + exact GELU over rows of 512.
__global__ __launch_bounds__(256) void lngelu_kernel(float* __restrict__ H,
    const float* __restrict__ g, const float* __restrict__ bb)
{
  int row = blockIdx.x;
  float* hr = H + (size_t)row * 512;
  int tid = threadIdx.x, lane = tid & 63, wv = tid >> 6;
  __shared__ double red[8];
  double x0 = (double)hr[tid], x1 = (double)hr[tid + 256];
  double s = x0 + x1;
#pragma unroll
  for (int off = 1; off < 64; off <<= 1) s += __shfl_xor(s, off);
  if (lane == 0) red[wv] = s;
  __syncthreads();
  double mu = (red[0] + red[1] + red[2] + red[3]) * (1.0 / 512.0);
  double d0 = x0 - mu, d1 = x1 - mu;
  double q = d0 * d0 + d1 * d1;
#pragma unroll
  for (int off = 1; off < 64; off <<= 1) q += __shfl_xor(q, off);
  if (lane == 0) red[4 + wv] = q;
  __syncthreads();
  double var = (red[4] + red[5] + red[6] + red[7]) * (1.0 / 512.0);
  double inv = 1.0 / sqrt(var + 1e-5);
  double y0 = d0 * inv * (double)g[tid]       + (double)bb[tid];
  double y1 = d1 * inv * (double)g[tid + 256] + (double)bb[tid + 256];
  const double ISQRT2 = 0.70710678118654752440;
  double z0 = 0.5 * y0 * (1.0 + erf(y0 * ISQRT2));
  double z1 = 0.5 * y1 * (1.0 + erf(y1 * ISQRT2));
  hr[tid] = (float)z0;
  hr[tid + 256] = (float)z1;
}

// Qp[token,m] = h[token,:] . w2[m,:] + b2[m] ; fp64 accumulate.
__global__ __launch_bounds__(256) void w2_kernel(const float* __restrict__ H,
    const float* __restrict__ W2, const float* __restrict__ B2,
    float* __restrict__ Qp)
{
  int gidx = blockIdx.x * 256 + threadIdx.x;  // 245*256 == 62720 exactly
  int token = gidx / 20, m = gidx % 20;
  const float* hr = H + (size_t)token * 512;
  const float* wr = W2 + (size_t)m * 512;
  double acc = 0.0;
  for (int k = 0; k < 512; k += 4) {
    float4 hv = *(const float4*)&hr[k];
    float4 wv = *(const float4*)&wr[k];
    acc += (double)hv.x * wv.x + (double)hv.y * wv.y +
           (double)hv.z * wv.z + (double)hv.w * wv.w;
  }
  Qp[gidx] = (float)(acc + (double)B2[m]);
}

// ---------------------------------------------------------------------------
// topk selection, v3: TWO tasks interleaved per wave (ILP across the two
// dependent binary-search chains) + scalarized counts (readfirstlane forces
// c into SGPRs -> s_cmp/s_cbranch, lo/hi stay uniform/scalar). Selection key
// = exact fp64 product bits (bit-exact vs float64 reference, ties by lower
// d). Emits 8 ballot words (mask) + qif per (bn,m).
// ---------------------------------------------------------------------------
__device__ __forceinline__ void topk_finish(
    const unsigned long long* u, unsigned long long thr, double qp,
    int g, unsigned long long* __restrict__ masks, float* __restrict__ qif,
    int lane)
{
  const int KSEL = 51;
  int cg = 0;
#pragma unroll
  for (int s = 0; s < 8; s++) cg += (int)__popcll(__ballot(u[s] > thr));
  cg = __builtin_amdgcn_readfirstlane(cg);
  int need_eq = KSEL - cg;  // how many ==thr to take, in increasing d order
  unsigned long long lmask = (1ULL << lane) - 1ULL;
  int base = 0;
  double ss = 0.0;
  unsigned long long selb[8];
#pragma unroll
  for (int s = 0; s < 8; s++) {
    bool iseq = (u[s] == thr);
    unsigned long long bal = __ballot((int)iseq);
    int rk = base + (int)__popcll(bal & lmask);
    bool sel = (u[s] > thr) || (iseq && rk < need_eq);
    base += (int)__popcll(bal);
    selb[s] = __ballot((int)sel);
    if (sel) {
      double ap = __longlong_as_double((long long)u[s]);  // |p|
      ss += ap * ap;
    }
  }
#pragma unroll
  for (int off = 1; off < 64; off <<= 1) ss += __shfl_xor(ss, off);
  double nrm = fabs(qp) * sqrt(ss);
  double qid = qp / fmax(nrm, 1e-6);
  if (lane == 0) {
    qif[g] = (float)qid;
#pragma unroll
    for (int s = 0; s < 8; s++) masks[(size_t)g * 8 + s] = selb[s];
  }
}

__global__ __launch_bounds__(256) void topk_select_kernel(
    const float* __restrict__ F, const float* __restrict__ T,
    const float* __restrict__ Qp, unsigned long long* __restrict__ masks,
    float* __restrict__ qif)
{
  const int KSEL = 51;
  int wid = blockIdx.x * 4 + (threadIdx.x >> 6);
  int lane = threadIdx.x & 63;
  int g0 = wid * 2;                 // two tasks, same bn (20 % 2 == 0)
  int bn = g0 / 20;
  int m0 = g0 - bn * 20;
  const float* Frow = F + (size_t)bn * 512;
  const float* T0 = T + (size_t)m0 * 512;
  const float* T1 = T0 + 512;

  unsigned long long u0[8], u1[8];
#pragma unroll
  for (int s = 0; s < 8; s++) {
    double fd = (double)Frow[lane + 64 * s];
    double p0 = fd * (double)T0[lane + 64 * s];   // exact in fp64
    double p1 = fd * (double)T1[lane + 64 * s];
    u0[s] = (unsigned long long)__double_as_longlong(p0) & 0x7fffffffffffffffULL;
    u1[s] = (unsigned long long)__double_as_longlong(p1) & 0x7fffffffffffffffULL;
  }

  unsigned long long lo0 = 0ULL, hi0 = 0x7ff0000000000000ULL;
  unsigned long long lo1 = 0ULL, hi1 = 0x7ff0000000000000ULL;
  bool dn0 = false, dn1 = false;
  while (!(dn0 && dn1)) {
    unsigned long long mid0 = lo0 + ((hi0 - lo0) >> 1);
    unsigned long long mid1 = lo1 + ((hi1 - lo1) >> 1);
    int c0 = 0, c1 = 0;
#pragma unroll
    for (int s = 0; s < 8; s++) {
      c0 += (int)__popcll(__ballot(u0[s] >= mid0));
      c1 += (int)__popcll(__ballot(u1[s] >= mid1));
    }
    c0 = __builtin_amdgcn_readfirstlane(c0);
    c1 = __builtin_amdgcn_readfirstlane(c1);
    if (!dn0) {
      if (c0 >= KSEL) { lo0 = mid0; dn0 = (c0 == KSEL); } else hi0 = mid0;
      dn0 = dn0 || (hi0 - lo0 <= 1ULL);
    }
    if (!dn1) {
      if (c1 >= KSEL) { lo1 = mid1; dn1 = (c1 == KSEL); } else hi1 = mid1;
      dn1 = dn1 || (hi1 - lo1 <= 1ULL);
    }
  }
  topk_finish(u0, lo0, (double)Qp[g0],     g0,     masks, qif, lane);
  topk_finish(u1, lo1, (double)Qp[g0 + 1], g0 + 1, masks, qif, lane);
}

// ---------------------------------------------------------------------------
// topk writeout v2: LDS value tile (two 256-d halves) -> fully coalesced
// contiguous float4 stores (R3-proven pattern, halved LDS for occupancy).
// ---------------------------------------------------------------------------
__global__ __launch_bounds__(256) void topk_write_kernel(
    const float* __restrict__ F, const float* __restrict__ T,
    const unsigned long long* __restrict__ masks,
    const float* __restrict__ qif, float* __restrict__ out)
{
  int bn = blockIdx.x;
  int tid = threadIdx.x;
  __shared__ unsigned long long mw[20][8];
  __shared__ float qf[20];
  __shared__ float vt[256][21];   // [d_local][m], stride 21: conflict-free
  if (tid < 160) ((unsigned long long*)mw)[tid] = masks[(size_t)bn * 160 + tid];
  if (tid < 20) qf[tid] = qif[(size_t)bn * 20 + tid];
  const float* Frow = F + (size_t)bn * 512;
  float* orow = out + (size_t)bn * 10240;
  __syncthreads();

#pragma unroll
  for (int half = 0; half < 2; half++) {
    int d = half * 256 + tid;
    float fd = Frow[d];
    int dw = d >> 6, db = d & 63;
#pragma unroll
    for (int m = 0; m < 20; m++) {
      bool sel = (mw[m][dw] >> db) & 1ULL;
      float tv = T[(size_t)m * 512 + d];
      vt[tid][m] = sel ? fd * tv * qf[m] : 0.0f;
    }
    __syncthreads();
#pragma unroll
    for (int k = 0; k < 5; k++) {
      int flat = (k * 256 + tid) * 4;     // element within half [0,5120)
      float v[4];
#pragma unroll
      for (int e = 0; e < 4; e++) {
        int fe = flat + e;
        int dl = fe / 20;
        int mm = fe - dl * 20;
        v[e] = vt[dl][mm];
      }
      float4 o = {v[0], v[1], v[2], v[3]};
      *(float4*)&orow[half * 5120 + flat] = o;
    }
    __syncthreads();
  }
}

extern "C" void kernel_launch(void* const* d_in, const int* in_sizes, int n_in,
                              void* d_out, int out_size, void* d_ws, size_t ws_size,
                              hipStream_t stream) {
  const float* F    = (const float*)d_in[0];   // [3136,512]
  const float* Wqkv = (const float*)d_in[1];   // [1536,512]
  const float* bqkv = (const float*)d_in[2];   // [1536]
  const float* Wo   = (const float*)d_in[3];   // [512,512]
  const float* bo   = (const float*)d_in[4];   // [512]
  const float* W1   = (const float*)d_in[5];   // [512,512]
  const float* b1   = (const float*)d_in[6];   // [512]
  const float* lng  = (const float*)d_in[7];   // [512]
  const float* lnb  = (const float*)d_in[8];   // [512]
  const float* W2   = (const float*)d_in[9];   // [20,512]
  const float* b2   = (const float*)d_in[10];  // [20]
  const float* Tm   = (const float*)d_in[11];  // [20,512]
  float* out = (float*)d_out;

  float* ws     = (float*)d_ws;
  float* qkv    = ws;                    // 4,816,896 fl
  float* scores = ws + 4816896;          // 4,917,248 fl
  float* Omg    = ws + 9734144;          // 1,605,632 fl
  float* Fenh   = ws + 11339776;         // 1,605,632 fl
  float* h1     = ws + 12945408;         // 1,605,632 fl
  float* Qp     = ws + 14551040;         // 62,720 fl
  // Overlays (lifetimes verified against launch order):
  //  - Fs+Wqkvs (3.59M fl-equiv) overlay scores; dead once qkv GEMM done,
  //    before scores GEMM writes.
  //  - Vt (1.84M fl) overlays Fenh(+h1 head); dead after PV, before Fenh/h1
  //    writes.
  //  - Omgs+Wos overlay scores; written after PV (scores dead), consumed by
  //    Fenh GEMM.
  //  - Fenhs+W1s overlay qkv (dead after PV); consumed by h1 GEMM.
  //  - masks+qif overlay qkv; written at select, after Fenhs is dead.
  float* Vt = Fenh;
  unsigned short* Fs    = (unsigned short*)scores;
  unsigned short* Wqkvs = (unsigned short*)(scores + 2408448);
  unsigned short* Omgs  = (unsigned short*)scores;
  unsigned short* Wos   = (unsigned short*)(scores + 2408448);
  unsigned short* Fenhs = (unsigned short*)qkv;
  unsigned short* W1s   = (unsigned short*)(qkv + 2408448);
  unsigned long long* masks = (unsigned long long*)qkv;
  float* qifb = (float*)(masks + (size_t)62720 * 8);
  dim3 blk(256);

  // 1) split F and Wqkv into bf16x3 limb planes (into dead scores region)
  split2_kernel<<<dim3(1168), blk, 0, stream>>>(
      F, Fs, 1605632, Wqkv, Wqkvs, 786432);

  // 2) qkv = F @ Wqkv^T + bqkv               [3136,1536]  (pre-split MFMA)
  gemm_ps3_kernel<<<dim3(25, 12), blk, 0, stream>>>(
      Fs, Wqkvs, qkv, bqkv, nullptr, 3136, 1536, 1536, 1605632LL, 786432LL);

  // 3) Vt[z][d][kk] = V[kk][d], zero-padded kk in [196,224)
  vtrans_kernel<<<dim3(128), blk, 0, stream>>>(qkv, Vt);

  // 4) scores[b,h] = Q[b,h] @ K[b,h]^T       [196,196] x 128  (on-the-fly)
  gemm_bf16x3_kernel<<<dim3(2, 2, 128), blk, 0, stream>>>(
      qkv, qkv + 512, scores, nullptr, nullptr,
      196, 196, 64, 1536, 1536, 196,
      8, 196LL * 1536, 64, 196LL * 1536, 64, 8LL * 38416, 38416);

  // 5) softmax rows (scale 0.125 inside)
  softmax_kernel<<<dim3(6272), blk, 0, stream>>>(scores);

  // 6) O[b,h] = P[b,h] @ Vt[b,h]^T           [196,64] x 128  (on-the-fly)
  gemm_bf16x3_kernel<<<dim3(2, 1, 128), blk, 0, stream>>>(
      scores, Vt, Omg, nullptr, nullptr,
      196, 64, 196, 196, 224, 512,
      8, 8LL * 38416, 38416, 8LL * 14336, 14336, 100352, 64);

  // 7) split Omg and Wo (scores is dead now)
  split2_kernel<<<dim3(912), blk, 0, stream>>>(
      Omg, Omgs, 1605632, Wo, Wos, 262144);

  // 8) F_enh = O @ Wo^T + bo + F_clean       (pre-split MFMA) [overwrites Vt]
  gemm_ps3_kernel<<<dim3(25, 4), blk, 0, stream>>>(
      Omgs, Wos, Fenh, bo, F, 3136, 512, 512, 1605632LL, 262144LL);

  // 9) split Fenh and W1 (qkv is dead now)
  split2_kernel<<<dim3(912), blk, 0, stream>>>(
      Fenh, Fenhs, 1605632, W1, W1s, 262144);

  // 10) h1 = F_enh @ W1^T + b1               (pre-split MFMA)
  gemm_ps3_kernel<<<dim3(25, 4), blk, 0, stream>>>(
      Fenhs, W1s, h1, b1, nullptr, 3136, 512, 512, 1605632LL, 262144LL);

  // 11) LayerNorm + exact GELU (in place)
  lngelu_kernel<<<dim3(3136), blk, 0, stream>>>(h1, lng, lnb);

  // 12) Qp = h1 @ W2^T + b2
  w2_kernel<<<dim3(245), blk, 0, stream>>>(h1, W2, b2, Qp);

  // 13) selection: 2 tasks per wave, scalarized counts [masks overlay qkv]
  topk_select_kernel<<<dim3(7840), blk, 0, stream>>>(F, Tm, Qp, masks, qifb);

  // 14) streaming writeout of [B,N,D,M], coalesced via LDS tile
  topk_write_kernel<<<dim3(3136), blk, 0, stream>>>(F, Tm, masks, qifb, out);
}

// Round 9
// 372.913 us; speedup vs baseline: 1.0610x; 1.0610x over previous
//
#include <hip/hip_runtime.h>
#include <cmath>

// ---------------------------------------------------------------------------
// Problem constants: B=16, N=196, D=512, M=20, H=8, hd=64, k=51
//   tokens = 3136, 3D = 1536
// ---------------------------------------------------------------------------

typedef __attribute__((ext_vector_type(8))) short bf16x8v;
typedef __attribute__((ext_vector_type(4))) float f32x4v;

__device__ __forceinline__ unsigned short f2bf_rne(float x) {
  unsigned u = __float_as_uint(x);
  u += 0x7fffu + ((u >> 16) & 1u);   // round-to-nearest-even
  return (unsigned short)(u >> 16);
}
__device__ __forceinline__ float bf2f(unsigned short h) {
  return __uint_as_float(((unsigned)h) << 16);
}

__device__ __forceinline__ void split3_8(const float* xs,
    bf16x8v& o0, bf16x8v& o1, bf16x8v& o2) {
#pragma unroll
  for (int e = 0; e < 8; e++) {
    float x = xs[e];
    unsigned short s0 = f2bf_rne(x); float r1 = x - bf2f(s0);
    unsigned short s1 = f2bf_rne(r1); float r2 = r1 - bf2f(s1);
    unsigned short s2 = f2bf_rne(r2);
    o0[e] = (short)s0; o1[e] = (short)s1; o2[e] = (short)s2;
  }
}

// ---------------------------------------------------------------------------
// split2: X -> 3 bf16 limb planes (plane stride = n elements). Handles two
// tensors per launch (fewer kernel launches). n0, n1 multiples of 2048.
// ---------------------------------------------------------------------------
__global__ __launch_bounds__(256) void split2_kernel(
    const float* __restrict__ X0, unsigned short* __restrict__ O0, int n0,
    const float* __restrict__ X1, unsigned short* __restrict__ O1, int n1)
{
  int nb0 = n0 >> 11;
  const float* X; unsigned short* O; long long i8, n;
  if ((int)blockIdx.x < nb0) {
    X = X0; O = O0; n = n0; i8 = (long long)blockIdx.x * 256 + threadIdx.x;
  } else {
    X = X1; O = O1; n = n1; i8 = (long long)(blockIdx.x - nb0) * 256 + threadIdx.x;
  }
  const float4 aa = *(const float4*)(X + i8 * 8);
  const float4 bb = *(const float4*)(X + i8 * 8 + 4);
  float xs[8] = {aa.x, aa.y, aa.z, aa.w, bb.x, bb.y, bb.z, bb.w};
  bf16x8v o0, o1, o2;
  split3_8(xs, o0, o1, o2);
  *(bf16x8v*)(O + i8 * 8)          = o0;
  *(bf16x8v*)(O + n + i8 * 8)      = o1;
  *(bf16x8v*)(O + 2 * n + i8 * 8)  = o2;
}

#define GBK 32
#define AROWB 80                 // LDS bytes per row (32 bf16 + 16B pad)
#define SPLIT_SZ (128 * AROWB)   // 10240 B per limb plane
#define BBASE (3 * SPLIT_SZ)     // B tile base: 30720

// ---------------------------------------------------------------------------
// Pre-split bf16x3 MFMA GEMM: C[i,j] = sum_k A[i,k]*B[j,k] (+bias[j])
// (+res[i,j]). As/Bs are 3-plane bf16 limb tensors (row stride 512, plane
// stride aPlane/bPlane elements). K=512 fixed. N%128==0 required; M guarded.
// Staging is pure 16B copies (no per-tile split VALU work).
// ---------------------------------------------------------------------------
__global__ __launch_bounds__(256) void gemm_ps3_kernel(
    const unsigned short* __restrict__ As, const unsigned short* __restrict__ Bs,
    float* __restrict__ C, const float* __restrict__ bias,
    const float* __restrict__ res,
    int M, int N, int ldc, long long aPlane, long long bPlane)
{
  __shared__ __align__(16) unsigned char smem[2 * BBASE];  // 61440 B

  int tid = threadIdx.x;
  int lane = tid & 63, w = tid >> 6;
  int wrow = w >> 1, wcol = w & 1;
  int i0 = blockIdx.x * 128, j0 = blockIdx.y * 128;

  int r = tid >> 1, hh = tid & 1;
  int arow = i0 + r; if (arow > M - 1) arow = M - 1;
  int brow = j0 + r; if (brow > N - 1) brow = N - 1;
  const unsigned short* ap = As + (size_t)arow * 512 + hh * 16;
  const unsigned short* bp = Bs + (size_t)brow * 512 + hh * 16;
  unsigned swoff = (unsigned)r * AROWB + (unsigned)hh * 32;

  f32x4v acc[4][4];
#pragma unroll
  for (int fi = 0; fi < 4; fi++)
#pragma unroll
    for (int fj = 0; fj < 4; fj++) acc[fi][fj] = (f32x4v){0.f, 0.f, 0.f, 0.f};

  unsigned fr_a = (unsigned)(wrow * 64 + (lane & 15)) * AROWB + (unsigned)(lane >> 4) * 16;
  unsigned fr_b = (unsigned)(wcol * 64 + (lane & 15)) * AROWB + (unsigned)(lane >> 4) * 16 + BBASE;

  for (int k0 = 0; k0 < 512; k0 += GBK) {
    bf16x8v a0[3], a1[3], b0v[3], b1v[3];
#pragma unroll
    for (int s = 0; s < 3; s++) {
      a0[s]  = *(const bf16x8v*)(ap + s * aPlane + k0);
      a1[s]  = *(const bf16x8v*)(ap + s * aPlane + k0 + 8);
      b0v[s] = *(const bf16x8v*)(bp + s * bPlane + k0);
      b1v[s] = *(const bf16x8v*)(bp + s * bPlane + k0 + 8);
    }
    __syncthreads();  // previous chunk's frag reads complete
#pragma unroll
    for (int s = 0; s < 3; s++) {
      *(bf16x8v*)(smem + s * SPLIT_SZ + swoff)              = a0[s];
      *(bf16x8v*)(smem + s * SPLIT_SZ + swoff + 16)         = a1[s];
      *(bf16x8v*)(smem + BBASE + s * SPLIT_SZ + swoff)      = b0v[s];
      *(bf16x8v*)(smem + BBASE + s * SPLIT_SZ + swoff + 16) = b1v[s];
    }
    __syncthreads();

    bf16x8v af[4][3];
#pragma unroll
    for (int fi = 0; fi < 4; fi++)
#pragma unroll
      for (int s = 0; s < 3; s++)
        af[fi][s] = *(const bf16x8v*)(smem + s * SPLIT_SZ + fr_a + fi * (16 * AROWB));

#pragma unroll
    for (int fj = 0; fj < 4; fj++) {
      bf16x8v b0 = *(const bf16x8v*)(smem + 0 * SPLIT_SZ + fr_b + fj * (16 * AROWB));
      bf16x8v b1 = *(const bf16x8v*)(smem + 1 * SPLIT_SZ + fr_b + fj * (16 * AROWB));
      bf16x8v b2 = *(const bf16x8v*)(smem + 2 * SPLIT_SZ + fr_b + fj * (16 * AROWB));
#pragma unroll
      for (int fi = 0; fi < 4; fi++) {
        f32x4v c = acc[fi][fj];
        c = __builtin_amdgcn_mfma_f32_16x16x32_bf16(af[fi][2], b0, c, 0, 0, 0);
        c = __builtin_amdgcn_mfma_f32_16x16x32_bf16(af[fi][1], b1, c, 0, 0, 0);
        c = __builtin_amdgcn_mfma_f32_16x16x32_bf16(af[fi][0], b2, c, 0, 0, 0);
        c = __builtin_amdgcn_mfma_f32_16x16x32_bf16(af[fi][1], b0, c, 0, 0, 0);
        c = __builtin_amdgcn_mfma_f32_16x16x32_bf16(af[fi][0], b1, c, 0, 0, 0);
        c = __builtin_amdgcn_mfma_f32_16x16x32_bf16(af[fi][0], b0, c, 0, 0, 0);
        acc[fi][fj] = c;
      }
    }
  }

#pragma unroll
  for (int fi = 0; fi < 4; fi++) {
    int row0 = i0 + wrow * 64 + fi * 16 + (lane >> 4) * 4;
#pragma unroll
    for (int fj = 0; fj < 4; fj++) {
      int col = j0 + wcol * 64 + fj * 16 + (lane & 15);
      if (col >= N) continue;
      float badd = bias ? bias[col] : 0.0f;
      f32x4v v = acc[fi][fj];
#pragma unroll
      for (int rr = 0; rr < 4; rr++) {
        int row = row0 + rr;
        if (row < M) {
          float o = v[rr] + badd;
          if (res) o += res[(size_t)row * ldc + col];
          C[(size_t)row * ldc + col] = o;
        }
      }
    }
  }
}

// ---------------------------------------------------------------------------
// On-the-fly bf16x3 MFMA GEMM (kept verbatim for the batched attention GEMMs:
// strided A/B with z-batching, K over-read with zero-padded B rows).
// ---------------------------------------------------------------------------
__global__ __launch_bounds__(256) void gemm_bf16x3_kernel(
    const float* __restrict__ A, const float* __restrict__ B,
    float* __restrict__ C, const float* __restrict__ bias,
    const float* __restrict__ res,
    int M, int N, int K, int lda, int ldb, int ldc,
    int zInner, long long aOuter, long long aInner,
    long long bOuter, long long bInner,
    long long cOuter, long long cInner)
{
  int z = blockIdx.z;
  int zo = z / zInner, zi = z % zInner;
  A += zo * aOuter + zi * aInner;
  B += zo * bOuter + zi * bInner;
  C += zo * cOuter + zi * cInner;

  __shared__ __align__(16) unsigned char smem[2 * BBASE];  // 61440 B

  int tid = threadIdx.x;
  int lane = tid & 63, w = tid >> 6;
  int wrow = w >> 1, wcol = w & 1;
  int i0 = blockIdx.x * 128, j0 = blockIdx.y * 128;

  int srow = tid >> 1;
  int skh  = tid & 1;
  int arow = i0 + srow; if (arow > M - 1) arow = M - 1;
  int brow = j0 + srow; if (brow > N - 1) brow = N - 1;
  const float* aptr = A + (size_t)arow * lda + skh * 16;
  const float* bptr = B + (size_t)brow * ldb + skh * 16;
  unsigned swoff = (unsigned)srow * AROWB + (unsigned)skh * 32;

  f32x4v acc[4][4];
#pragma unroll
  for (int fi = 0; fi < 4; fi++)
#pragma unroll
    for (int fj = 0; fj < 4; fj++) acc[fi][fj] = (f32x4v){0.f, 0.f, 0.f, 0.f};

  unsigned fr_a = (unsigned)(wrow * 64 + (lane & 15)) * AROWB + (unsigned)(lane >> 4) * 16;
  unsigned fr_b = (unsigned)(wcol * 64 + (lane & 15)) * AROWB + (unsigned)(lane >> 4) * 16 + BBASE;

  for (int k0 = 0; k0 < K; k0 += GBK) {
    float av[16], bv[16];
    {
      const float4 q0 = *(const float4*)(aptr + k0);
      const float4 q1 = *(const float4*)(aptr + k0 + 4);
      const float4 q2 = *(const float4*)(aptr + k0 + 8);
      const float4 q3 = *(const float4*)(aptr + k0 + 12);
      av[0]=q0.x; av[1]=q0.y; av[2]=q0.z; av[3]=q0.w;
      av[4]=q1.x; av[5]=q1.y; av[6]=q1.z; av[7]=q1.w;
      av[8]=q2.x; av[9]=q2.y; av[10]=q2.z; av[11]=q2.w;
      av[12]=q3.x; av[13]=q3.y; av[14]=q3.z; av[15]=q3.w;
      const float4 r0 = *(const float4*)(bptr + k0);
      const float4 r1 = *(const float4*)(bptr + k0 + 4);
      const float4 r2 = *(const float4*)(bptr + k0 + 8);
      const float4 r3 = *(const float4*)(bptr + k0 + 12);
      bv[0]=r0.x; bv[1]=r0.y; bv[2]=r0.z; bv[3]=r0.w;
      bv[4]=r1.x; bv[5]=r1.y; bv[6]=r1.z; bv[7]=r1.w;
      bv[8]=r2.x; bv[9]=r2.y; bv[10]=r2.z; bv[11]=r2.w;
      bv[12]=r3.x; bv[13]=r3.y; bv[14]=r3.z; bv[15]=r3.w;
    }
    unsigned short ha[3][16], hb[3][16];
#pragma unroll
    for (int e = 0; e < 16; e++) {
      float x = av[e];
      unsigned short s0 = f2bf_rne(x); float r = x - bf2f(s0);
      unsigned short s1 = f2bf_rne(r); float r2 = r - bf2f(s1);
      unsigned short s2 = f2bf_rne(r2);
      ha[0][e] = s0; ha[1][e] = s1; ha[2][e] = s2;
      float y = bv[e];
      unsigned short t0 = f2bf_rne(y); float u = y - bf2f(t0);
      unsigned short t1 = f2bf_rne(u); float u2 = u - bf2f(t1);
      unsigned short t2 = f2bf_rne(u2);
      hb[0][e] = t0; hb[1][e] = t1; hb[2][e] = t2;
    }
    __syncthreads();
#pragma unroll
    for (int s = 0; s < 3; s++) {
      bf16x8v v0, v1, w0, w1;
#pragma unroll
      for (int e = 0; e < 8; e++) {
        v0[e] = (short)ha[s][e]; v1[e] = (short)ha[s][8 + e];
        w0[e] = (short)hb[s][e]; w1[e] = (short)hb[s][8 + e];
      }
      *(bf16x8v*)(smem + s * SPLIT_SZ + swoff)              = v0;
      *(bf16x8v*)(smem + s * SPLIT_SZ + swoff + 16)         = v1;
      *(bf16x8v*)(smem + BBASE + s * SPLIT_SZ + swoff)      = w0;
      *(bf16x8v*)(smem + BBASE + s * SPLIT_SZ + swoff + 16) = w1;
    }
    __syncthreads();

    bf16x8v af[4][3];
#pragma unroll
    for (int fi = 0; fi < 4; fi++)
#pragma unroll
      for (int s = 0; s < 3; s++)
        af[fi][s] = *(const bf16x8v*)(smem + s * SPLIT_SZ + fr_a + fi * (16 * AROWB));

#pragma unroll
    for (int fj = 0; fj < 4; fj++) {
      bf16x8v b0 = *(const bf16x8v*)(smem + 0 * SPLIT_SZ + fr_b + fj * (16 * AROWB));
      bf16x8v b1 = *(const bf16x8v*)(smem + 1 * SPLIT_SZ + fr_b + fj * (16 * AROWB));
      bf16x8v b2 = *(const bf16x8v*)(smem + 2 * SPLIT_SZ + fr_b + fj * (16 * AROWB));
#pragma unroll
      for (int fi = 0; fi < 4; fi++) {
        f32x4v c = acc[fi][fj];
        c = __builtin_amdgcn_mfma_f32_16x16x32_bf16(af[fi][2], b0, c, 0, 0, 0);
        c = __builtin_amdgcn_mfma_f32_16x16x32_bf16(af[fi][1], b1, c, 0, 0, 0);
        c = __builtin_amdgcn_mfma_f32_16x16x32_bf16(af[fi][0], b2, c, 0, 0, 0);
        c = __builtin_amdgcn_mfma_f32_16x16x32_bf16(af[fi][1], b0, c, 0, 0, 0);
        c = __builtin_amdgcn_mfma_f32_16x16x32_bf16(af[fi][0], b1, c, 0, 0, 0);
        c = __builtin_amdgcn_mfma_f32_16x16x32_bf16(af[fi][0], b0, c, 0, 0, 0);
        acc[fi][fj] = c;
      }
    }
  }

#pragma unroll
  for (int fi = 0; fi < 4; fi++) {
    int row0 = i0 + wrow * 64 + fi * 16 + (lane >> 4) * 4;
#pragma unroll
    for (int fj = 0; fj < 4; fj++) {
      int col = j0 + wcol * 64 + fj * 16 + (lane & 15);
      if (col >= N) continue;
      float badd = bias ? bias[col] : 0.0f;
      f32x4v v = acc[fi][fj];
#pragma unroll
      for (int rr = 0; rr < 4; rr++) {
        int row = row0 + rr;
        if (row < M) {
          float o = v[rr] + badd;
          if (res) o += res[(size_t)row * ldc + col];
          C[(size_t)row * ldc + col] = o;
        }
      }
    }
  }
}

// ---------------------------------------------------------------------------
// V transpose: per z=(b*8+h), Vt[z][d=64][kk=224] = V[kk][d] (kk>=196 -> 0).
// ---------------------------------------------------------------------------
__global__ __launch_bounds__(256) void vtrans_kernel(
    const float* __restrict__ qkv, float* __restrict__ Vt)
{
  __shared__ float lds[224 * 65];
  int z = blockIdx.x;
  int b = z >> 3, h = z & 7;
  int tid = threadIdx.x;
  const float* src = qkv + ((size_t)b * 196) * 1536 + 1024 + h * 64;
  for (int idx = tid; idx < 224 * 64; idx += 256) {
    int kk = idx >> 6, d = idx & 63;
    lds[kk * 65 + d] = (kk < 196) ? src[(size_t)kk * 1536 + d] : 0.0f;
  }
  __syncthreads();
  float* dst = Vt + (size_t)z * (64 * 224);
  for (int idx = tid; idx < 64 * 224; idx += 256) {
    int d = idx / 224, kk = idx - d * 224;
    dst[idx] = lds[kk * 65 + d];
  }
}

// In-place row softmax of scaled scores: rows of length 196, scale 1/sqrt(64).
__global__ __launch_bounds__(256) void softmax_kernel(float* __restrict__ S)
{
  int row = blockIdx.x * 4 + (threadIdx.x >> 6);
  int lane = threadIdx.x & 63;
  float* sr = S + (size_t)row * 196;
  double v[4];
#pragma unroll
  for (int t = 0; t < 4; t++) {
    int j = lane + 64 * t;
    v[t] = (j < 196) ? (double)sr[j] * 0.125 : -1e300;
  }
  double mx = fmax(fmax(v[0], v[1]), fmax(v[2], v[3]));
#pragma unroll
  for (int off = 1; off < 64; off <<= 1) mx = fmax(mx, __shfl_xor(mx, off));
  double e[4]; double s = 0.0;
#pragma unroll
  for (int t = 0; t < 4; t++) {
    int j = lane + 64 * t;
    e[t] = (j < 196) ? exp(v[t] - mx) : 0.0;
    s += e[t];
  }
#pragma unroll
  for (int off = 1; off < 64; off <<= 1) s += __shfl_xor(s, off);
  double inv = 1.0 / s;
#pragma unroll
  for (int t = 0; t < 4; t++) {
    int j = lane + 64 * t;
    if (j < 196) sr[j] = (float)(e[t] * inv);
  }
}

// In-place LayerNorm (ddof=0, eps=1e-5) + exact GELU over rows of 512.
__global__ __launch_bounds__(256) void lngelu_kernel(float* __restrict__ H,
    const float* __restrict__ g, const float* __restrict__ bb)
{
  int row = blockIdx.x;
  float* hr = H + (size_t)row * 512;
  int tid = threadIdx.x, lane = tid & 63, wv = tid >> 6;
  __shared__ double red[8];
  double x0 = (double)hr[tid], x1 = (double)hr[tid + 256];
  double s = x0 + x1;
#pragma unroll
  for (int off = 1; off < 64; off <<= 1) s += __shfl_xor(s, off);
  if (lane == 0) red[wv] = s;
  __syncthreads();
  double mu = (red[0] + red[1] + red[2] + red[3]) * (1.0 / 512.0);
  double d0 = x0 - mu, d1 = x1 - mu;
  double q = d0 * d0 + d1 * d1;
#pragma unroll
  for (int off = 1; off < 64; off <<= 1) q += __shfl_xor(q, off);
  if (lane == 0) red[4 + wv] = q;
  __syncthreads();
  double var = (red[4] + red[5] + red[6] + red[7]) * (1.0 / 512.0);
  double inv = 1.0 / sqrt(var + 1e-5);
  double y0 = d0 * inv * (double)g[tid]       + (double)bb[tid];
  double y1 = d1 * inv * (double)g[tid + 256] + (double)bb[tid + 256];
  const double ISQRT2 = 0.70710678118654752440;
  double z0 = 0.5 * y0 * (1.0 + erf(y0 * ISQRT2));
  double z1 = 0.5 * y1 * (1.0 + erf(y1 * ISQRT2));
  hr[tid] = (float)z0;
  hr[tid + 256] = (float)z1;
}

// Qp[token,m] = h[token,:] . w2[m,:] + b2[m] ; fp64 accumulate.
__global__ __launch_bounds__(256) void w2_kernel(const float* __restrict__ H,
    const float* __restrict__ W2, const float* __restrict__ B2,
    float* __restrict__ Qp)
{
  int gidx = blockIdx.x * 256 + threadIdx.x;  // 245*256 == 62720 exactly
  int token = gidx / 20, m = gidx % 20;
  const float* hr = H + (size_t)token * 512;
  const float* wr = W2 + (size_t)m * 512;
  double acc = 0.0;
  for (int k = 0; k < 512; k += 4) {
    float4 hv = *(const float4*)&hr[k];
    float4 wv = *(const float4*)&wr[k];
    acc += (double)hv.x * wv.x + (double)hv.y * wv.y +
           (double)hv.z * wv.z + (double)hv.w * wv.w;
  }
  Qp[gidx] = (float)(acc + (double)B2[m]);
}

// ---------------------------------------------------------------------------
// topk selection, v4: one wave per (bn,m). 32-bit PREFIX binary search
// (uh = top 32 bits of the exact |F*T| double bits — order-preserving), range
// seeded by wave min/max, early exit when count==51 (prefix then fully
// determines the set). Rare prefix-tie boundary resolved EXACTLY by
// (low-32 desc, d asc) max-extraction. Finish math in fp32 (reference is
// fp32). Emits 8 ballot words (mask) + qif per (bn,m).
// ---------------------------------------------------------------------------
__global__ __launch_bounds__(256) void topk_select_kernel(
    const float* __restrict__ F, const float* __restrict__ T,
    const float* __restrict__ Qp, unsigned long long* __restrict__ masks,
    float* __restrict__ qif)
{
  const int KSEL = 51;
  int g = blockIdx.x * 4 + (threadIdx.x >> 6);   // (bn, m) task id
  int lane = threadIdx.x & 63;
  int bn = g / 20, m = g - bn * 20;
  const float* Frow = F + (size_t)bn * 512;
  const float* Trow = T + (size_t)m * 512;

  unsigned uh[8], ul[8];
  float apf[8];
#pragma unroll
  for (int s = 0; s < 8; s++) {
    double p = (double)Frow[lane + 64 * s] * (double)Trow[lane + 64 * s];  // exact
    unsigned long long u =
        (unsigned long long)__double_as_longlong(p) & 0x7fffffffffffffffULL;
    uh[s] = (unsigned)(u >> 32);
    ul[s] = (unsigned)u;
    apf[s] = (float)fabs(p);
  }

  // seed range [min, max+1] via one packed wave reduce
  unsigned mx = 0u, mn = 0xffffffffu;
#pragma unroll
  for (int s = 0; s < 8; s++) {
    mx = uh[s] > mx ? uh[s] : mx;
    mn = uh[s] < mn ? uh[s] : mn;
  }
#pragma unroll
  for (int off = 1; off < 64; off <<= 1) {
    unsigned omx = __shfl_xor(mx, off);
    unsigned omn = __shfl_xor(mn, off);
    mx = omx > mx ? omx : mx;
    mn = omn < mn ? omn : mn;
  }

  unsigned lo = mn, hi = mx + 1u;   // count(>=lo)=512>=51; count(>=hi)=0<51
  bool exact = false;
  while (hi - lo > 1u) {
    unsigned mid = lo + ((hi - lo) >> 1);
    int c = 0;
#pragma unroll
    for (int s = 0; s < 8; s++) c += (int)__popcll(__ballot(uh[s] >= mid));
    if (c >= KSEL) { lo = mid; if (c == KSEL) { exact = true; break; } }
    else hi = mid;
  }
  unsigned thrh = lo;

  bool sel[8];
  if (exact) {
    // prefix >= thrh selects exactly 51 keys; prefix dominance makes this
    // identical to full-64-bit selection.
#pragma unroll
    for (int s = 0; s < 8; s++) sel[s] = (uh[s] >= thrh);
  } else {
    // boundary prefix has >=2 ties; take (51 - count(>thrh)) of them ranked
    // by low-32 desc then d asc — exact full-key order with index tiebreak.
    int cg = 0;
#pragma unroll
    for (int s = 0; s < 8; s++) {
      sel[s] = (uh[s] > thrh);
      cg += (int)__popcll(__ballot(sel[s]));
    }
    int need = KSEL - cg;   // wave-uniform (from ballots)
    bool tk[8];
#pragma unroll
    for (int s = 0; s < 8; s++) tk[s] = false;
    while (need > 0) {
      unsigned long long bk = 0ULL;
#pragma unroll
      for (int s = 0; s < 8; s++) {
        if (uh[s] == thrh && !tk[s]) {
          unsigned long long key = (1ULL << 41)
                                 | ((unsigned long long)ul[s] << 9)
                                 | ((unsigned long long)(7 - s) << 6)
                                 | (unsigned long long)(63 - lane);
          bk = key > bk ? key : bk;
        }
      }
#pragma unroll
      for (int off = 1; off < 64; off <<= 1) {
        unsigned long long ob = __shfl_xor(bk, off);
        bk = ob > bk ? ob : bk;
      }
      if ((int)(63 - (bk & 63ULL)) == lane) {
        int ws = 7 - (int)((bk >> 6) & 7ULL);
        sel[ws] = true;
        tk[ws] = true;
      }
      need--;
    }
  }

  float ss = 0.f;
  unsigned long long selb[8];
#pragma unroll
  for (int s = 0; s < 8; s++) {
    selb[s] = __ballot((int)sel[s]);
    if (sel[s]) ss += apf[s] * apf[s];
  }
#pragma unroll
  for (int off = 1; off < 64; off <<= 1) ss += __shfl_xor(ss, off);
  float qp = Qp[g];
  float nrm = fabsf(qp) * sqrtf(ss);
  float qid = qp / fmaxf(nrm, 1e-6f);
  if (lane == 0) {
    qif[g] = qid;
#pragma unroll
    for (int s = 0; s < 8; s++) masks[(size_t)g * 8 + s] = selb[s];
  }
}

// ---------------------------------------------------------------------------
// topk writeout: LDS value tile (two 256-d halves) -> fully coalesced
// contiguous float4 stores.
// ---------------------------------------------------------------------------
__global__ __launch_bounds__(256) void topk_write_kernel(
    const float* __restrict__ F, const float* __restrict__ T,
    const unsigned long long* __restrict__ masks,
    const float* __restrict__ qif, float* __restrict__ out)
{
  int bn = blockIdx.x;
  int tid = threadIdx.x;
  __shared__ unsigned long long mw[20][8];
  __shared__ float qf[20];
  __shared__ float vt[256][21];   // [d_local][m], stride 21: conflict-free
  if (tid < 160) ((unsigned long long*)mw)[tid] = masks[(size_t)bn * 160 + tid];
  if (tid < 20) qf[tid] = qif[(size_t)bn * 20 + tid];
  const float* Frow = F + (size_t)bn * 512;
  float* orow = out + (size_t)bn * 10240;
  __syncthreads();

#pragma unroll
  for (int half = 0; half < 2; half++) {
    int d = half * 256 + tid;
    float fd = Frow[d];
    int dw = d >> 6, db = d & 63;
#pragma unroll
    for (int m = 0; m < 20; m++) {
      bool sel = (mw[m][dw] >> db) & 1ULL;
      float tv = T[(size_t)m * 512 + d];
      vt[tid][m] = sel ? fd * tv * qf[m] : 0.0f;
    }
    __syncthreads();
#pragma unroll
    for (int k = 0; k < 5; k++) {
      int flat = (k * 256 + tid) * 4;     // element within half [0,5120)
      float v[4];
#pragma unroll
      for (int e = 0; e < 4; e++) {
        int fe = flat + e;
        int dl = fe / 20;
        int mm = fe - dl * 20;
        v[e] = vt[dl][mm];
      }
      float4 o = {v[0], v[1], v[2], v[3]};
      *(float4*)&orow[half * 5120 + flat] = o;
    }
    __syncthreads();
  }
}

extern "C" void kernel_launch(void* const* d_in, const int* in_sizes, int n_in,
                              void* d_out, int out_size, void* d_ws, size_t ws_size,
                              hipStream_t stream) {
  const float* F    = (const float*)d_in[0];   // [3136,512]
  const float* Wqkv = (const float*)d_in[1];   // [1536,512]
  const float* bqkv = (const float*)d_in[2];   // [1536]
  const float* Wo   = (const float*)d_in[3];   // [512,512]
  const float* bo   = (const float*)d_in[4];   // [512]
  const float* W1   = (const float*)d_in[5];   // [512,512]
  const float* b1   = (const float*)d_in[6];   // [512]
  const float* lng  = (const float*)d_in[7];   // [512]
  const float* lnb  = (const float*)d_in[8];   // [512]
  const float* W2   = (const float*)d_in[9];   // [20,512]
  const float* b2   = (const float*)d_in[10];  // [20]
  const float* Tm   = (const float*)d_in[11];  // [20,512]
  float* out = (float*)d_out;

  float* ws     = (float*)d_ws;
  float* qkv    = ws;                    // 4,816,896 fl
  float* scores = ws + 4816896;          // 4,917,248 fl
  float* Omg    = ws + 9734144;          // 1,605,632 fl
  float* Fenh   = ws + 11339776;         // 1,605,632 fl
  float* h1     = ws + 12945408;         // 1,605,632 fl
  float* Qp     = ws + 14551040;         // 62,720 fl
  // Overlays (lifetimes verified against launch order):
  //  - Fs+Wqkvs overlay scores; dead once qkv GEMM done, before scores write.
  //  - Vt overlays Fenh(+h1 head); dead after PV, before Fenh/h1 writes.
  //  - Omgs+Wos overlay scores; written after PV (scores dead).
  //  - Fenhs+W1s overlay qkv (dead after PV); consumed by h1 GEMM.
  //  - masks+qif overlay qkv; written at select, after Fenhs is dead.
  float* Vt = Fenh;
  unsigned short* Fs    = (unsigned short*)scores;
  unsigned short* Wqkvs = (unsigned short*)(scores + 2408448);
  unsigned short* Omgs  = (unsigned short*)scores;
  unsigned short* Wos   = (unsigned short*)(scores + 2408448);
  unsigned short* Fenhs = (unsigned short*)qkv;
  unsigned short* W1s   = (unsigned short*)(qkv + 2408448);
  unsigned long long* masks = (unsigned long long*)qkv;
  float* qifb = (float*)(masks + (size_t)62720 * 8);
  dim3 blk(256);

  // 1) split F and Wqkv into bf16x3 limb planes (into dead scores region)
  split2_kernel<<<dim3(1168), blk, 0, stream>>>(
      F, Fs, 1605632, Wqkv, Wqkvs, 786432);

  // 2) qkv = F @ Wqkv^T + bqkv               [3136,1536]  (pre-split MFMA)
  gemm_ps3_kernel<<<dim3(25, 12), blk, 0, stream>>>(
      Fs, Wqkvs, qkv, bqkv, nullptr, 3136, 1536, 1536, 1605632LL, 786432LL);

  // 3) Vt[z][d][kk] = V[kk][d], zero-padded kk in [196,224)
  vtrans_kernel<<<dim3(128), blk, 0, stream>>>(qkv, Vt);

  // 4) scores[b,h] = Q[b,h] @ K[b,h]^T       [196,196] x 128  (on-the-fly)
  gemm_bf16x3_kernel<<<dim3(2, 2, 128), blk, 0, stream>>>(
      qkv, qkv + 512, scores, nullptr, nullptr,
      196, 196, 64, 1536, 1536, 196,
      8, 196LL * 1536, 64, 196LL * 1536, 64, 8LL * 38416, 38416);

  // 5) softmax rows (scale 0.125 inside)
  softmax_kernel<<<dim3(6272), blk, 0, stream>>>(scores);

  // 6) O[b,h] = P[b,h] @ Vt[b,h]^T           [196,64] x 128  (on-the-fly)
  gemm_bf16x3_kernel<<<dim3(2, 1, 128), blk, 0, stream>>>(
      scores, Vt, Omg, nullptr, nullptr,
      196, 64, 196, 196, 224, 512,
      8, 8LL * 38416, 38416, 8LL * 14336, 14336, 100352, 64);

  // 7) split Omg and Wo (scores is dead now)
  split2_kernel<<<dim3(912), blk, 0, stream>>>(
      Omg, Omgs, 1605632, Wo, Wos, 262144);

  // 8) F_enh = O @ Wo^T + bo + F_clean       (pre-split MFMA) [overwrites Vt]
  gemm_ps3_kernel<<<dim3(25, 4), blk, 0, stream>>>(
      Omgs, Wos, Fenh, bo, F, 3136, 512, 512, 1605632LL, 262144LL);

  // 9) split Fenh and W1 (qkv is dead now)
  split2_kernel<<<dim3(912), blk, 0, stream>>>(
      Fenh, Fenhs, 1605632, W1, W1s, 262144);

  // 10) h1 = F_enh @ W1^T + b1               (pre-split MFMA)
  gemm_ps3_kernel<<<dim3(25, 4), blk, 0, stream>>>(
      Fenhs, W1s, h1, b1, nullptr, 3136, 512, 512, 1605632LL, 262144LL);

  // 11) LayerNorm + exact GELU (in place)
  lngelu_kernel<<<dim3(3136), blk, 0, stream>>>(h1, lng, lnb);

  // 12) Qp = h1 @ W2^T + b2
  w2_kernel<<<dim3(245), blk, 0, stream>>>(h1, W2, b2, Qp);

  // 13) selection: one wave per (bn,m), 32-bit prefix search
  topk_select_kernel<<<dim3(15680), blk, 0, stream>>>(F, Tm, Qp, masks, qifb);

  // 14) streaming writeout of [B,N,D,M], coalesced via LDS tile
  topk_write_kernel<<<dim3(3136), blk, 0, stream>>>(F, Tm, masks, qifb, out);
}

// Round 10
// 370.079 us; speedup vs baseline: 1.0691x; 1.0077x over previous
//
#include <hip/hip_runtime.h>
#include <cmath>

// ---------------------------------------------------------------------------
// Problem constants: B=16, N=196, D=512, M=20, H=8, hd=64, k=51
//   tokens = 3136, 3D = 1536
// ---------------------------------------------------------------------------

typedef __attribute__((ext_vector_type(8))) short bf16x8v;
typedef __attribute__((ext_vector_type(4))) float f32x4v;

__device__ __forceinline__ unsigned short f2bf_rne(float x) {
  unsigned u = __float_as_uint(x);
  u += 0x7fffu + ((u >> 16) & 1u);   // round-to-nearest-even
  return (unsigned short)(u >> 16);
}
__device__ __forceinline__ float bf2f(unsigned short h) {
  return __uint_as_float(((unsigned)h) << 16);
}
__device__ __forceinline__ void split3_1(float x,
    unsigned short& s0, unsigned short& s1, unsigned short& s2) {
  s0 = f2bf_rne(x); float r1 = x - bf2f(s0);
  s1 = f2bf_rne(r1); float r2 = r1 - bf2f(s1);
  s2 = f2bf_rne(r2);
}
__device__ __forceinline__ void split3_8(const float* xs,
    bf16x8v& o0, bf16x8v& o1, bf16x8v& o2) {
#pragma unroll
  for (int e = 0; e < 8; e++) {
    unsigned short a, b, c;
    split3_1(xs[e], a, b, c);
    o0[e] = (short)a; o1[e] = (short)b; o2[e] = (short)c;
  }
}

// ---------------------------------------------------------------------------
// split4: four tensors -> 3 bf16 limb planes each, one launch.
// n_i multiples of 2048.
// ---------------------------------------------------------------------------
__global__ __launch_bounds__(256) void split4_kernel(
    const float* __restrict__ X0, unsigned short* __restrict__ O0, int n0,
    const float* __restrict__ X1, unsigned short* __restrict__ O1, int n1,
    const float* __restrict__ X2, unsigned short* __restrict__ O2, int n2,
    const float* __restrict__ X3, unsigned short* __restrict__ O3, int n3)
{
  int nb0 = n0 >> 11, nb1 = n1 >> 11, nb2 = n2 >> 11;
  int b = blockIdx.x;
  const float* X; unsigned short* O; long long i8, n;
  if (b < nb0)                   { X = X0; O = O0; n = n0; i8 = (long long)b * 256 + threadIdx.x; }
  else if (b < nb0 + nb1)        { X = X1; O = O1; n = n1; i8 = (long long)(b - nb0) * 256 + threadIdx.x; }
  else if (b < nb0 + nb1 + nb2)  { X = X2; O = O2; n = n2; i8 = (long long)(b - nb0 - nb1) * 256 + threadIdx.x; }
  else                           { X = X3; O = O3; n = n3; i8 = (long long)(b - nb0 - nb1 - nb2) * 256 + threadIdx.x; }
  const float4 aa = *(const float4*)(X + i8 * 8);
  const float4 bb = *(const float4*)(X + i8 * 8 + 4);
  float xs[8] = {aa.x, aa.y, aa.z, aa.w, bb.x, bb.y, bb.z, bb.w};
  bf16x8v o0, o1, o2;
  split3_8(xs, o0, o1, o2);
  *(bf16x8v*)(O + i8 * 8)          = o0;
  *(bf16x8v*)(O + n + i8 * 8)      = o1;
  *(bf16x8v*)(O + 2 * n + i8 * 8)  = o2;
}

#define GBK 32
#define AROWB 80                 // LDS bytes per row (32 bf16 + 16B pad)
#define SPLIT_SZ (128 * AROWB)   // 10240 B per limb plane
#define BBASE (3 * SPLIT_SZ)     // B tile base: 30720

// ---------------------------------------------------------------------------
// Pre-split bf16x3 MFMA GEMM. As/Bs are 3-plane bf16 limb tensors (row stride
// 512, plane strides aPlane/bPlane). K=512 fixed. N%128==0; M guarded.
// Output: if Cl!=null, write bf16x3 LIMBS of the result (3 planes, stride
// clPlane) and skip f32 C; else write f32 C. res/bias applied before split.
// ---------------------------------------------------------------------------
__global__ __launch_bounds__(256) void gemm_ps3_kernel(
    const unsigned short* __restrict__ As, const unsigned short* __restrict__ Bs,
    float* __restrict__ C, const float* __restrict__ bias,
    const float* __restrict__ res,
    int M, int N, int ldc, long long aPlane, long long bPlane,
    unsigned short* __restrict__ Cl, long long clPlane)
{
  __shared__ __align__(16) unsigned char smem[2 * BBASE];  // 61440 B

  int tid = threadIdx.x;
  int lane = tid & 63, w = tid >> 6;
  int wrow = w >> 1, wcol = w & 1;
  int i0 = blockIdx.x * 128, j0 = blockIdx.y * 128;

  int r = tid >> 1, hh = tid & 1;
  int arow = i0 + r; if (arow > M - 1) arow = M - 1;
  int brow = j0 + r; if (brow > N - 1) brow = N - 1;
  const unsigned short* ap = As + (size_t)arow * 512 + hh * 16;
  const unsigned short* bp = Bs + (size_t)brow * 512 + hh * 16;
  unsigned swoff = (unsigned)r * AROWB + (unsigned)hh * 32;

  f32x4v acc[4][4];
#pragma unroll
  for (int fi = 0; fi < 4; fi++)
#pragma unroll
    for (int fj = 0; fj < 4; fj++) acc[fi][fj] = (f32x4v){0.f, 0.f, 0.f, 0.f};

  unsigned fr_a = (unsigned)(wrow * 64 + (lane & 15)) * AROWB + (unsigned)(lane >> 4) * 16;
  unsigned fr_b = (unsigned)(wcol * 64 + (lane & 15)) * AROWB + (unsigned)(lane >> 4) * 16 + BBASE;

  for (int k0 = 0; k0 < 512; k0 += GBK) {
    bf16x8v a0[3], a1[3], b0v[3], b1v[3];
#pragma unroll
    for (int s = 0; s < 3; s++) {
      a0[s]  = *(const bf16x8v*)(ap + s * aPlane + k0);
      a1[s]  = *(const bf16x8v*)(ap + s * aPlane + k0 + 8);
      b0v[s] = *(const bf16x8v*)(bp + s * bPlane + k0);
      b1v[s] = *(const bf16x8v*)(bp + s * bPlane + k0 + 8);
    }
    __syncthreads();  // previous chunk's frag reads complete
#pragma unroll
    for (int s = 0; s < 3; s++) {
      *(bf16x8v*)(smem + s * SPLIT_SZ + swoff)              = a0[s];
      *(bf16x8v*)(smem + s * SPLIT_SZ + swoff + 16)         = a1[s];
      *(bf16x8v*)(smem + BBASE + s * SPLIT_SZ + swoff)      = b0v[s];
      *(bf16x8v*)(smem + BBASE + s * SPLIT_SZ + swoff + 16) = b1v[s];
    }
    __syncthreads();

    bf16x8v af[4][3];
#pragma unroll
    for (int fi = 0; fi < 4; fi++)
#pragma unroll
      for (int s = 0; s < 3; s++)
        af[fi][s] = *(const bf16x8v*)(smem + s * SPLIT_SZ + fr_a + fi * (16 * AROWB));

#pragma unroll
    for (int fj = 0; fj < 4; fj++) {
      bf16x8v b0 = *(const bf16x8v*)(smem + 0 * SPLIT_SZ + fr_b + fj * (16 * AROWB));
      bf16x8v b1 = *(const bf16x8v*)(smem + 1 * SPLIT_SZ + fr_b + fj * (16 * AROWB));
      bf16x8v b2 = *(const bf16x8v*)(smem + 2 * SPLIT_SZ + fr_b + fj * (16 * AROWB));
#pragma unroll
      for (int fi = 0; fi < 4; fi++) {
        f32x4v c = acc[fi][fj];
        c = __builtin_amdgcn_mfma_f32_16x16x32_bf16(af[fi][2], b0, c, 0, 0, 0);
        c = __builtin_amdgcn_mfma_f32_16x16x32_bf16(af[fi][1], b1, c, 0, 0, 0);
        c = __builtin_amdgcn_mfma_f32_16x16x32_bf16(af[fi][0], b2, c, 0, 0, 0);
        c = __builtin_amdgcn_mfma_f32_16x16x32_bf16(af[fi][1], b0, c, 0, 0, 0);
        c = __builtin_amdgcn_mfma_f32_16x16x32_bf16(af[fi][0], b1, c, 0, 0, 0);
        c = __builtin_amdgcn_mfma_f32_16x16x32_bf16(af[fi][0], b0, c, 0, 0, 0);
        acc[fi][fj] = c;
      }
    }
  }

#pragma unroll
  for (int fi = 0; fi < 4; fi++) {
    int row0 = i0 + wrow * 64 + fi * 16 + (lane >> 4) * 4;
#pragma unroll
    for (int fj = 0; fj < 4; fj++) {
      int col = j0 + wcol * 64 + fj * 16 + (lane & 15);
      if (col >= N) continue;
      float badd = bias ? bias[col] : 0.0f;
      f32x4v v = acc[fi][fj];
#pragma unroll
      for (int rr = 0; rr < 4; rr++) {
        int row = row0 + rr;
        if (row < M) {
          float o = v[rr] + badd;
          if (res) o += res[(size_t)row * ldc + col];
          size_t idx = (size_t)row * ldc + col;
          if (Cl) {
            unsigned short l0, l1, l2;
            split3_1(o, l0, l1, l2);
            Cl[idx] = l0; Cl[idx + clPlane] = l1; Cl[idx + 2 * clPlane] = l2;
          } else {
            C[idx] = o;
          }
        }
      }
    }
  }
}

// ---------------------------------------------------------------------------
// On-the-fly bf16x3 MFMA GEMM (batched attention GEMMs: strided A/B with
// z-batching, K over-read with zero-padded B rows). Optional limb output.
// ---------------------------------------------------------------------------
__global__ __launch_bounds__(256) void gemm_bf16x3_kernel(
    const float* __restrict__ A, const float* __restrict__ B,
    float* __restrict__ C, const float* __restrict__ bias,
    const float* __restrict__ res,
    int M, int N, int K, int lda, int ldb, int ldc,
    int zInner, long long aOuter, long long aInner,
    long long bOuter, long long bInner,
    long long cOuter, long long cInner,
    unsigned short* __restrict__ Cl, long long clPlane)
{
  int z = blockIdx.z;
  int zo = z / zInner, zi = z % zInner;
  A += zo * aOuter + zi * aInner;
  B += zo * bOuter + zi * bInner;
  long long coff = zo * cOuter + zi * cInner;
  if (C) C += coff;
  if (Cl) Cl += coff;

  __shared__ __align__(16) unsigned char smem[2 * BBASE];  // 61440 B

  int tid = threadIdx.x;
  int lane = tid & 63, w = tid >> 6;
  int wrow = w >> 1, wcol = w & 1;
  int i0 = blockIdx.x * 128, j0 = blockIdx.y * 128;

  int srow = tid >> 1;
  int skh  = tid & 1;
  int arow = i0 + srow; if (arow > M - 1) arow = M - 1;
  int brow = j0 + srow; if (brow > N - 1) brow = N - 1;
  const float* aptr = A + (size_t)arow * lda + skh * 16;
  const float* bptr = B + (size_t)brow * ldb + skh * 16;
  unsigned swoff = (unsigned)srow * AROWB + (unsigned)skh * 32;

  f32x4v acc[4][4];
#pragma unroll
  for (int fi = 0; fi < 4; fi++)
#pragma unroll
    for (int fj = 0; fj < 4; fj++) acc[fi][fj] = (f32x4v){0.f, 0.f, 0.f, 0.f};

  unsigned fr_a = (unsigned)(wrow * 64 + (lane & 15)) * AROWB + (unsigned)(lane >> 4) * 16;
  unsigned fr_b = (unsigned)(wcol * 64 + (lane & 15)) * AROWB + (unsigned)(lane >> 4) * 16 + BBASE;

  for (int k0 = 0; k0 < K; k0 += GBK) {
    float av[16], bv[16];
    {
      const float4 q0 = *(const float4*)(aptr + k0);
      const float4 q1 = *(const float4*)(aptr + k0 + 4);
      const float4 q2 = *(const float4*)(aptr + k0 + 8);
      const float4 q3 = *(const float4*)(aptr + k0 + 12);
      av[0]=q0.x; av[1]=q0.y; av[2]=q0.z; av[3]=q0.w;
      av[4]=q1.x; av[5]=q1.y; av[6]=q1.z; av[7]=q1.w;
      av[8]=q2.x; av[9]=q2.y; av[10]=q2.z; av[11]=q2.w;
      av[12]=q3.x; av[13]=q3.y; av[14]=q3.z; av[15]=q3.w;
      const float4 r0 = *(const float4*)(bptr + k0);
      const float4 r1 = *(const float4*)(bptr + k0 + 4);
      const float4 r2 = *(const float4*)(bptr + k0 + 8);
      const float4 r3 = *(const float4*)(bptr + k0 + 12);
      bv[0]=r0.x; bv[1]=r0.y; bv[2]=r0.z; bv[3]=r0.w;
      bv[4]=r1.x; bv[5]=r1.y; bv[6]=r1.z; bv[7]=r1.w;
      bv[8]=r2.x; bv[9]=r2.y; bv[10]=r2.z; bv[11]=r2.w;
      bv[12]=r3.x; bv[13]=r3.y; bv[14]=r3.z; bv[15]=r3.w;
    }
    unsigned short ha[3][16], hb[3][16];
#pragma unroll
    for (int e = 0; e < 16; e++) {
      split3_1(av[e], ha[0][e], ha[1][e], ha[2][e]);
      split3_1(bv[e], hb[0][e], hb[1][e], hb[2][e]);
    }
    __syncthreads();
#pragma unroll
    for (int s = 0; s < 3; s++) {
      bf16x8v v0, v1, w0, w1;
#pragma unroll
      for (int e = 0; e < 8; e++) {
        v0[e] = (short)ha[s][e]; v1[e] = (short)ha[s][8 + e];
        w0[e] = (short)hb[s][e]; w1[e] = (short)hb[s][8 + e];
      }
      *(bf16x8v*)(smem + s * SPLIT_SZ + swoff)              = v0;
      *(bf16x8v*)(smem + s * SPLIT_SZ + swoff + 16)         = v1;
      *(bf16x8v*)(smem + BBASE + s * SPLIT_SZ + swoff)      = w0;
      *(bf16x8v*)(smem + BBASE + s * SPLIT_SZ + swoff + 16) = w1;
    }
    __syncthreads();

    bf16x8v af[4][3];
#pragma unroll
    for (int fi = 0; fi < 4; fi++)
#pragma unroll
      for (int s = 0; s < 3; s++)
        af[fi][s] = *(const bf16x8v*)(smem + s * SPLIT_SZ + fr_a + fi * (16 * AROWB));

#pragma unroll
    for (int fj = 0; fj < 4; fj++) {
      bf16x8v b0 = *(const bf16x8v*)(smem + 0 * SPLIT_SZ + fr_b + fj * (16 * AROWB));
      bf16x8v b1 = *(const bf16x8v*)(smem + 1 * SPLIT_SZ + fr_b + fj * (16 * AROWB));
      bf16x8v b2 = *(const bf16x8v*)(smem + 2 * SPLIT_SZ + fr_b + fj * (16 * AROWB));
#pragma unroll
      for (int fi = 0; fi < 4; fi++) {
        f32x4v c = acc[fi][fj];
        c = __builtin_amdgcn_mfma_f32_16x16x32_bf16(af[fi][2], b0, c, 0, 0, 0);
        c = __builtin_amdgcn_mfma_f32_16x16x32_bf16(af[fi][1], b1, c, 0, 0, 0);
        c = __builtin_amdgcn_mfma_f32_16x16x32_bf16(af[fi][0], b2, c, 0, 0, 0);
        c = __builtin_amdgcn_mfma_f32_16x16x32_bf16(af[fi][1], b0, c, 0, 0, 0);
        c = __builtin_amdgcn_mfma_f32_16x16x32_bf16(af[fi][0], b1, c, 0, 0, 0);
        c = __builtin_amdgcn_mfma_f32_16x16x32_bf16(af[fi][0], b0, c, 0, 0, 0);
        acc[fi][fj] = c;
      }
    }
  }

#pragma unroll
  for (int fi = 0; fi < 4; fi++) {
    int row0 = i0 + wrow * 64 + fi * 16 + (lane >> 4) * 4;
#pragma unroll
    for (int fj = 0; fj < 4; fj++) {
      int col = j0 + wcol * 64 + fj * 16 + (lane & 15);
      if (col >= N) continue;
      float badd = bias ? bias[col] : 0.0f;
      f32x4v v = acc[fi][fj];
#pragma unroll
      for (int rr = 0; rr < 4; rr++) {
        int row = row0 + rr;
        if (row < M) {
          float o = v[rr] + badd;
          if (res) o += res[(size_t)row * ldc + col];
          size_t idx = (size_t)row * ldc + col;
          if (Cl) {
            unsigned short l0, l1, l2;
            split3_1(o, l0, l1, l2);
            Cl[idx] = l0; Cl[idx + clPlane] = l1; Cl[idx + 2 * clPlane] = l2;
          } else {
            C[idx] = o;
          }
        }
      }
    }
  }
}

// ---------------------------------------------------------------------------
// V transpose: per z=(b*8+h), Vt[z][d=64][kk=224] = V[kk][d] (kk>=196 -> 0).
// ---------------------------------------------------------------------------
__global__ __launch_bounds__(256) void vtrans_kernel(
    const float* __restrict__ qkv, float* __restrict__ Vt)
{
  __shared__ float lds[224 * 65];
  int z = blockIdx.x;
  int b = z >> 3, h = z & 7;
  int tid = threadIdx.x;
  const float* src = qkv + ((size_t)b * 196) * 1536 + 1024 + h * 64;
  for (int idx = tid; idx < 224 * 64; idx += 256) {
    int kk = idx >> 6, d = idx & 63;
    lds[kk * 65 + d] = (kk < 196) ? src[(size_t)kk * 1536 + d] : 0.0f;
  }
  __syncthreads();
  float* dst = Vt + (size_t)z * (64 * 224);
  for (int idx = tid; idx < 64 * 224; idx += 256) {
    int d = idx / 224, kk = idx - d * 224;
    dst[idx] = lds[kk * 65 + d];
  }
}

// In-place row softmax of scaled scores: rows of length 196, scale 1/sqrt(64).
__global__ __launch_bounds__(256) void softmax_kernel(float* __restrict__ S)
{
  int row = blockIdx.x * 4 + (threadIdx.x >> 6);
  int lane = threadIdx.x & 63;
  float* sr = S + (size_t)row * 196;
  double v[4];
#pragma unroll
  for (int t = 0; t < 4; t++) {
    int j = lane + 64 * t;
    v[t] = (j < 196) ? (double)sr[j] * 0.125 : -1e300;
  }
  double mx = fmax(fmax(v[0], v[1]), fmax(v[2], v[3]));
#pragma unroll
  for (int off = 1; off < 64; off <<= 1) mx = fmax(mx, __shfl_xor(mx, off));
  double e[4]; double s = 0.0;
#pragma unroll
  for (int t = 0; t < 4; t++) {
    int j = lane + 64 * t;
    e[t] = (j < 196) ? exp(v[t] - mx) : 0.0;
    s += e[t];
  }
#pragma unroll
  for (int off = 1; off < 64; off <<= 1) s += __shfl_xor(s, off);
  double inv = 1.0 / s;
#pragma unroll
  for (int t = 0; t < 4; t++) {
    int j = lane + 64 * t;
    if (j < 196) sr[j] = (float)(e[t] * inv);
  }
}

// ---------------------------------------------------------------------------
// Fused LayerNorm (ddof=0, eps=1e-5) + exact GELU + w2 projection.
// Block per token row: LN+GELU in fp64 (identical math to prior kernels),
// GELU'd row staged in LDS, then 4 waves x 5 m fp64-accumulated dots.
// ---------------------------------------------------------------------------
__global__ __launch_bounds__(256) void lnw2_kernel(
    const float* __restrict__ H, const float* __restrict__ g,
    const float* __restrict__ bb, const float* __restrict__ W2,
    const float* __restrict__ B2, float* __restrict__ Qp)
{
  int row = blockIdx.x;
  const float* hr = H + (size_t)row * 512;
  int tid = threadIdx.x, lane = tid & 63, wv = tid >> 6;
  __shared__ double red[8];
  __shared__ float y[512];
  double x0 = (double)hr[tid], x1 = (double)hr[tid + 256];
  double s = x0 + x1;
#pragma unroll
  for (int off = 1; off < 64; off <<= 1) s += __shfl_xor(s, off);
  if (lane == 0) red[wv] = s;
  __syncthreads();
  double mu = (red[0] + red[1] + red[2] + red[3]) * (1.0 / 512.0);
  double d0 = x0 - mu, d1 = x1 - mu;
  double q = d0 * d0 + d1 * d1;
#pragma unroll
  for (int off = 1; off < 64; off <<= 1) q += __shfl_xor(q, off);
  if (lane == 0) red[4 + wv] = q;
  __syncthreads();
  double var = (red[4] + red[5] + red[6] + red[7]) * (1.0 / 512.0);
  double inv = 1.0 / sqrt(var + 1e-5);
  double y0 = d0 * inv * (double)g[tid]       + (double)bb[tid];
  double y1 = d1 * inv * (double)g[tid + 256] + (double)bb[tid + 256];
  const double ISQRT2 = 0.70710678118654752440;
  double z0 = 0.5 * y0 * (1.0 + erf(y0 * ISQRT2));
  double z1 = 0.5 * y1 * (1.0 + erf(y1 * ISQRT2));
  y[tid] = (float)z0;
  y[tid + 256] = (float)z1;
  __syncthreads();

#pragma unroll 1
  for (int t = 0; t < 5; t++) {
    int m = wv * 5 + t;
    const float* wr = W2 + (size_t)m * 512;
    double acc = 0.0;
#pragma unroll
    for (int sE = 0; sE < 8; sE++) {
      int j = lane + 64 * sE;
      acc += (double)y[j] * (double)wr[j];
    }
#pragma unroll
    for (int off = 1; off < 64; off <<= 1) acc += __shfl_xor(acc, off);
    if (lane == 0) Qp[(size_t)row * 20 + m] = (float)(acc + (double)B2[m]);
  }
}

// ---------------------------------------------------------------------------
// topk selection v5: TWO tasks per wave with FULLY GUARDED per-task ballot
// blocks (R6's flaw was unguarded ballots). 32-bit prefix search, min/max
// seeding, early exit at count==51; rare prefix-tie boundary resolved exactly
// by (low-32 desc, d asc). fp32 finish.
// ---------------------------------------------------------------------------
__device__ __forceinline__ void topk_finish32(
    const unsigned* uh, const unsigned* ul, const float* apf,
    unsigned thrh, bool exact, float qp, int g,
    unsigned long long* __restrict__ masks, float* __restrict__ qif, int lane)
{
  const int KSEL = 51;
  bool sel[8];
  if (exact) {
#pragma unroll
    for (int s = 0; s < 8; s++) sel[s] = (uh[s] >= thrh);
  } else {
    int cg = 0;
#pragma unroll
    for (int s = 0; s < 8; s++) {
      sel[s] = (uh[s] > thrh);
      cg += (int)__popcll(__ballot(sel[s]));
    }
    int need = KSEL - cg;
    bool tk[8];
#pragma unroll
    for (int s = 0; s < 8; s++) tk[s] = false;
    while (need > 0) {
      unsigned long long bk = 0ULL;
#pragma unroll
      for (int s = 0; s < 8; s++) {
        if (uh[s] == thrh && !tk[s]) {
          unsigned long long key = (1ULL << 41)
                                 | ((unsigned long long)ul[s] << 9)
                                 | ((unsigned long long)(7 - s) << 6)
                                 | (unsigned long long)(63 - lane);
          bk = key > bk ? key : bk;
        }
      }
#pragma unroll
      for (int off = 1; off < 64; off <<= 1) {
        unsigned long long ob = __shfl_xor(bk, off);
        bk = ob > bk ? ob : bk;
      }
      if ((int)(63 - (bk & 63ULL)) == lane) {
        int wsI = 7 - (int)((bk >> 6) & 7ULL);
        sel[wsI] = true;
        tk[wsI] = true;
      }
      need--;
    }
  }

  float ss = 0.f;
  unsigned long long selb[8];
#pragma unroll
  for (int s = 0; s < 8; s++) {
    selb[s] = __ballot((int)sel[s]);
    if (sel[s]) ss += apf[s] * apf[s];
  }
#pragma unroll
  for (int off = 1; off < 64; off <<= 1) ss += __shfl_xor(ss, off);
  float nrm = fabsf(qp) * sqrtf(ss);
  float qid = qp / fmaxf(nrm, 1e-6f);
  if (lane == 0) {
    qif[g] = qid;
#pragma unroll
    for (int s = 0; s < 8; s++) masks[(size_t)g * 8 + s] = selb[s];
  }
}

__global__ __launch_bounds__(256) void topk_select_kernel(
    const float* __restrict__ F, const float* __restrict__ T,
    const float* __restrict__ Qp, unsigned long long* __restrict__ masks,
    float* __restrict__ qif)
{
  const int KSEL = 51;
  int wid = blockIdx.x * 4 + (threadIdx.x >> 6);
  int lane = threadIdx.x & 63;
  int g0 = wid * 2;                 // two tasks, same bn (20 % 2 == 0)
  int bn = g0 / 20, m0 = g0 - bn * 20;
  const float* Frow = F + (size_t)bn * 512;
  const float* T0r = T + (size_t)m0 * 512;
  const float* T1r = T0r + 512;

  unsigned uh0[8], ul0[8], uh1[8], ul1[8];
  float ap0[8], ap1[8];
#pragma unroll
  for (int s = 0; s < 8; s++) {
    double fd = (double)Frow[lane + 64 * s];
    double p0 = fd * (double)T0r[lane + 64 * s];   // exact in fp64
    double p1 = fd * (double)T1r[lane + 64 * s];
    unsigned long long u0 =
        (unsigned long long)__double_as_longlong(p0) & 0x7fffffffffffffffULL;
    unsigned long long u1 =
        (unsigned long long)__double_as_longlong(p1) & 0x7fffffffffffffffULL;
    uh0[s] = (unsigned)(u0 >> 32); ul0[s] = (unsigned)u0;
    uh1[s] = (unsigned)(u1 >> 32); ul1[s] = (unsigned)u1;
    ap0[s] = (float)fabs(p0); ap1[s] = (float)fabs(p1);
  }

  unsigned mx0 = 0u, mn0 = 0xffffffffu, mx1 = 0u, mn1 = 0xffffffffu;
#pragma unroll
  for (int s = 0; s < 8; s++) {
    mx0 = uh0[s] > mx0 ? uh0[s] : mx0;  mn0 = uh0[s] < mn0 ? uh0[s] : mn0;
    mx1 = uh1[s] > mx1 ? uh1[s] : mx1;  mn1 = uh1[s] < mn1 ? uh1[s] : mn1;
  }
#pragma unroll
  for (int off = 1; off < 64; off <<= 1) {
    unsigned a = __shfl_xor(mx0, off); mx0 = a > mx0 ? a : mx0;
    unsigned b = __shfl_xor(mn0, off); mn0 = b < mn0 ? b : mn0;
    unsigned c = __shfl_xor(mx1, off); mx1 = c > mx1 ? c : mx1;
    unsigned d = __shfl_xor(mn1, off); mn1 = d < mn1 ? d : mn1;
  }

  unsigned lo0 = mn0, hi0 = mx0 + 1u, lo1 = mn1, hi1 = mx1 + 1u;
  bool ex0 = false, ex1 = false;
  bool dn0 = (hi0 - lo0 <= 1u), dn1 = (hi1 - lo1 <= 1u);
  while (!(dn0 && dn1)) {
    if (!dn0) {   // wave-uniform guard: ballots skipped once task 0 is done
      unsigned mid = lo0 + ((hi0 - lo0) >> 1);
      int c = 0;
#pragma unroll
      for (int s = 0; s < 8; s++) c += (int)__popcll(__ballot(uh0[s] >= mid));
      if (c >= KSEL) { lo0 = mid; if (c == KSEL) { ex0 = true; dn0 = true; } }
      else hi0 = mid;
      dn0 = dn0 || (hi0 - lo0 <= 1u);
    }
    if (!dn1) {
      unsigned mid = lo1 + ((hi1 - lo1) >> 1);
      int c = 0;
#pragma unroll
      for (int s = 0; s < 8; s++) c += (int)__popcll(__ballot(uh1[s] >= mid));
      if (c >= KSEL) { lo1 = mid; if (c == KSEL) { ex1 = true; dn1 = true; } }
      else hi1 = mid;
      dn1 = dn1 || (hi1 - lo1 <= 1u);
    }
  }
  topk_finish32(uh0, ul0, ap0, lo0, ex0, Qp[g0],     g0,     masks, qif, lane);
  topk_finish32(uh1, ul1, ap1, lo1, ex1, Qp[g0 + 1], g0 + 1, masks, qif, lane);
}

// ---------------------------------------------------------------------------
// topk writeout: LDS value tile (two 256-d halves) -> fully coalesced
// contiguous float4 stores.
// ---------------------------------------------------------------------------
__global__ __launch_bounds__(256) void topk_write_kernel(
    const float* __restrict__ F, const float* __restrict__ T,
    const unsigned long long* __restrict__ masks,
    const float* __restrict__ qif, float* __restrict__ out)
{
  int bn = blockIdx.x;
  int tid = threadIdx.x;
  __shared__ unsigned long long mw[20][8];
  __shared__ float qf[20];
  __shared__ float vt[256][21];   // [d_local][m], stride 21: conflict-free
  if (tid < 160) ((unsigned long long*)mw)[tid] = masks[(size_t)bn * 160 + tid];
  if (tid < 20) qf[tid] = qif[(size_t)bn * 20 + tid];
  const float* Frow = F + (size_t)bn * 512;
  float* orow = out + (size_t)bn * 10240;
  __syncthreads();

#pragma unroll
  for (int half = 0; half < 2; half++) {
    int d = half * 256 + tid;
    float fd = Frow[d];
    int dw = d >> 6, db = d & 63;
#pragma unroll
    for (int m = 0; m < 20; m++) {
      bool sel = (mw[m][dw] >> db) & 1ULL;
      float tv = T[(size_t)m * 512 + d];
      vt[tid][m] = sel ? fd * tv * qf[m] : 0.0f;
    }
    __syncthreads();
#pragma unroll
    for (int k = 0; k < 5; k++) {
      int flat = (k * 256 + tid) * 4;     // element within half [0,5120)
      float v[4];
#pragma unroll
      for (int e = 0; e < 4; e++) {
        int fe = flat + e;
        int dl = fe / 20;
        int mm = fe - dl * 20;
        v[e] = vt[dl][mm];
      }
      float4 o = {v[0], v[1], v[2], v[3]};
      *(float4*)&orow[half * 5120 + flat] = o;
    }
    __syncthreads();
  }
}

extern "C" void kernel_launch(void* const* d_in, const int* in_sizes, int n_in,
                              void* d_out, int out_size, void* d_ws, size_t ws_size,
                              hipStream_t stream) {
  const float* F    = (const float*)d_in[0];   // [3136,512]
  const float* Wqkv = (const float*)d_in[1];   // [1536,512]
  const float* bqkv = (const float*)d_in[2];   // [1536]
  const float* Wo   = (const float*)d_in[3];   // [512,512]
  const float* bo   = (const float*)d_in[4];   // [512]
  const float* W1   = (const float*)d_in[5];   // [512,512]
  const float* b1   = (const float*)d_in[6];   // [512]
  const float* lng  = (const float*)d_in[7];   // [512]
  const float* lnb  = (const float*)d_in[8];   // [512]
  const float* W2   = (const float*)d_in[9];   // [20,512]
  const float* b2   = (const float*)d_in[10];  // [20]
  const float* Tm   = (const float*)d_in[11];  // [20,512]
  float* out = (float*)d_out;

  float* ws     = (float*)d_ws;
  // Layout (floats). Lifetimes verified against launch order:
  //  - qkv [0, 4.82M): written step 2, consumed steps 3/4; dead after PV.
  //    masks+qif overlay it (written at select).
  //  - scores [4.82M, 9.73M): Fs+Wqkvs overlay start (dead after qkv GEMM,
  //    before scores GEMM writes). scores dead after PV.
  //  - Vt, h1, Qp, Wos, W1s, Omgs, Fenhs: dedicated regions (no overlap).
  float* qkv    = ws;                          // 4,816,896
  float* scores = ws + 4816896;                // 4,917,248
  float* Vt     = ws + 9734144;                // 1,835,008
  float* h1     = ws + 11569152;               // 1,605,632
  float* Qp     = ws + 13174784;               //    62,720
  unsigned short* Wos   = (unsigned short*)(ws + 13237504);  // 393,216 fl
  unsigned short* W1s   = (unsigned short*)(ws + 13630720);  // 393,216 fl
  unsigned short* Omgs  = (unsigned short*)(ws + 14023936);  // 2,408,448 fl
  unsigned short* Fenhs = (unsigned short*)(ws + 16432384);  // 2,408,448 fl
  unsigned short* Fs    = (unsigned short*)scores;
  unsigned short* Wqkvs = (unsigned short*)(scores + 2408448);
  unsigned long long* masks = (unsigned long long*)qkv;
  float* qifb = (float*)(masks + (size_t)62720 * 8);
  dim3 blk(256);

  // 1) split F, Wqkv, Wo, W1 into bf16x3 limb planes (one launch)
  split4_kernel<<<dim3(1424), blk, 0, stream>>>(
      F, Fs, 1605632, Wqkv, Wqkvs, 786432,
      Wo, Wos, 262144, W1, W1s, 262144);

  // 2) qkv = F @ Wqkv^T + bqkv               [3136,1536]  (pre-split MFMA)
  gemm_ps3_kernel<<<dim3(25, 12), blk, 0, stream>>>(
      Fs, Wqkvs, qkv, bqkv, nullptr, 3136, 1536, 1536, 1605632LL, 786432LL,
      nullptr, 0);

  // 3) Vt[z][d][kk] = V[kk][d], zero-padded kk in [196,224)
  vtrans_kernel<<<dim3(128), blk, 0, stream>>>(qkv, Vt);

  // 4) scores[b,h] = Q[b,h] @ K[b,h]^T       [196,196] x 128  (on-the-fly)
  gemm_bf16x3_kernel<<<dim3(2, 2, 128), blk, 0, stream>>>(
      qkv, qkv + 512, scores, nullptr, nullptr,
      196, 196, 64, 1536, 1536, 196,
      8, 196LL * 1536, 64, 196LL * 1536, 64, 8LL * 38416, 38416,
      nullptr, 0);

  // 5) softmax rows (scale 0.125 inside)
  softmax_kernel<<<dim3(6272), blk, 0, stream>>>(scores);

  // 6) O[b,h] = P[b,h] @ Vt[b,h]^T -> Omg LIMBS directly (no f32 Omg)
  gemm_bf16x3_kernel<<<dim3(2, 1, 128), blk, 0, stream>>>(
      scores, Vt, nullptr, nullptr, nullptr,
      196, 64, 196, 196, 224, 512,
      8, 8LL * 38416, 38416, 8LL * 14336, 14336, 100352, 64,
      Omgs, 1605632LL);

  // 7) F_enh = O @ Wo^T + bo + F_clean -> Fenh LIMBS directly
  gemm_ps3_kernel<<<dim3(25, 4), blk, 0, stream>>>(
      Omgs, Wos, nullptr, bo, F, 3136, 512, 512, 1605632LL, 262144LL,
      Fenhs, 1605632LL);

  // 8) h1 = F_enh @ W1^T + b1               (pre-split MFMA)
  gemm_ps3_kernel<<<dim3(25, 4), blk, 0, stream>>>(
      Fenhs, W1s, h1, b1, nullptr, 3136, 512, 512, 1605632LL, 262144LL,
      nullptr, 0);

  // 9) fused LayerNorm + exact GELU + w2 -> Qp
  lnw2_kernel<<<dim3(3136), blk, 0, stream>>>(h1, lng, lnb, W2, b2, Qp);

  // 10) selection: 2 tasks/wave, guarded ballots [masks overlay dead qkv]
  topk_select_kernel<<<dim3(7840), blk, 0, stream>>>(F, Tm, Qp, masks, qifb);

  // 11) streaming writeout of [B,N,D,M], coalesced via LDS tile
  topk_write_kernel<<<dim3(3136), blk, 0, stream>>>(F, Tm, masks, qifb, out);
}

// Round 11
// 316.001 us; speedup vs baseline: 1.2521x; 1.1711x over previous
//
#include <hip/hip_runtime.h>
#include <cmath>

// ---------------------------------------------------------------------------
// Problem constants: B=16, N=196, D=512, M=20, H=8, hd=64, k=51
//   tokens = 3136, 3D = 1536
// Algebra: h1 = Omg@(W1*Wo)^T + F@W1^T + (W1*bo + b1)  [Fenh eliminated]
// ---------------------------------------------------------------------------

typedef __attribute__((ext_vector_type(8))) short bf16x8v;
typedef __attribute__((ext_vector_type(4))) float f32x4v;

__device__ __forceinline__ unsigned short f2bf_rne(float x) {
  unsigned u = __float_as_uint(x);
  u += 0x7fffu + ((u >> 16) & 1u);   // round-to-nearest-even
  return (unsigned short)(u >> 16);
}
__device__ __forceinline__ float bf2f(unsigned short h) {
  return __uint_as_float(((unsigned)h) << 16);
}
__device__ __forceinline__ void split3_1(float x,
    unsigned short& s0, unsigned short& s1, unsigned short& s2) {
  s0 = f2bf_rne(x); float r1 = x - bf2f(s0);
  s1 = f2bf_rne(r1); float r2 = r1 - bf2f(s1);
  s2 = f2bf_rne(r2);
}

// ---------------------------------------------------------------------------
// prep mega-kernel: block ranges do independent jobs.
//  [0,784)        split F        -> Fs     (pstride 1605632)
//  [784,1168)     split Wqkv     -> Walls  rows 0..1535  (pstride 1048576)
//  [1168,1296)    split W1       -> Walls  rows 1536..2047 (pstride 1048576)
//  [1296,1360)    Wc = W1 @ Wo (fp32 FMA + fp64 chunks) -> Wcs limbs
//  [1360,1472)    zero Vt pad (kk in [196,224))
//  1472           bcomb[n] = sum_i W1[n,i]*bo[i] + b1[n]
//  1473           biasAll = concat(bqkv, zeros[512])
// ---------------------------------------------------------------------------
__global__ __launch_bounds__(256) void prep_kernel(
    const float* __restrict__ F, unsigned short* __restrict__ Fs,
    const float* __restrict__ Wqkv, const float* __restrict__ W1,
    unsigned short* __restrict__ Walls,
    const float* __restrict__ Wo, unsigned short* __restrict__ Wcs,
    float* __restrict__ Vt,
    const float* __restrict__ bo, const float* __restrict__ b1,
    float* __restrict__ bcomb,
    const float* __restrict__ bqkv, float* __restrict__ biasAll)
{
  int b = blockIdx.x;
  int tid = threadIdx.x;

  if (b < 1296) {  // ---- splits ----
    const float* X; unsigned short* O; long long i8, pstride;
    if (b < 784)       { X = F;    O = Fs;              pstride = 1605632; i8 = (long long)b * 256 + tid; }
    else if (b < 1168) { X = Wqkv; O = Walls;           pstride = 1048576; i8 = (long long)(b - 784) * 256 + tid; }
    else               { X = W1;   O = Walls + 786432;  pstride = 1048576; i8 = (long long)(b - 1168) * 256 + tid; }
    const float4 aa = *(const float4*)(X + i8 * 8);
    const float4 bb = *(const float4*)(X + i8 * 8 + 4);
    float xs[8] = {aa.x, aa.y, aa.z, aa.w, bb.x, bb.y, bb.z, bb.w};
    bf16x8v o0, o1, o2;
#pragma unroll
    for (int e = 0; e < 8; e++) {
      unsigned short s0, s1, s2;
      split3_1(xs[e], s0, s1, s2);
      o0[e] = (short)s0; o1[e] = (short)s1; o2[e] = (short)s2;
    }
    *(bf16x8v*)(O + i8 * 8)               = o0;
    *(bf16x8v*)(O + pstride + i8 * 8)     = o1;
    *(bf16x8v*)(O + 2 * pstride + i8 * 8) = o2;
    return;
  }

  if (b < 1360) {  // ---- Wc = W1 @ Wo, 64x64 tile, bTrans=0, limb output ----
    __shared__ __align__(16) float As[16][68];
    __shared__ __align__(16) float Bs[16][68];
    int local = b - 1296;
    int i0 = (local >> 3) * 64, j0 = (local & 7) * 64;
    int tx = tid & 15, ty = tid >> 4;
    double acc[4][4];
#pragma unroll
    for (int i = 0; i < 4; i++)
#pragma unroll
      for (int j = 0; j < 4; j++) acc[i][j] = 0.0;
    for (int k0 = 0; k0 < 512; k0 += 16) {
#pragma unroll
      for (int rr = 0; rr < 4; rr++) {
        int r = ty + 16 * rr;
        As[tx][r] = W1[(size_t)(i0 + r) * 512 + k0 + tx];
      }
      {
        int j = tid & 63, c0 = (tid >> 6) * 4;
#pragma unroll
        for (int cc = 0; cc < 4; cc++) {
          int c = c0 + cc;
          Bs[c][j] = Wo[(size_t)(k0 + c) * 512 + j0 + j];
        }
      }
      __syncthreads();
      float cf[4][4];
#pragma unroll
      for (int i = 0; i < 4; i++)
#pragma unroll
        for (int j = 0; j < 4; j++) cf[i][j] = 0.0f;
#pragma unroll
      for (int kk = 0; kk < 16; kk++) {
        float4 a4 = *(const float4*)&As[kk][ty * 4];
        float4 b4 = *(const float4*)&Bs[kk][tx * 4];
        float av[4] = {a4.x, a4.y, a4.z, a4.w};
        float bv[4] = {b4.x, b4.y, b4.z, b4.w};
#pragma unroll
        for (int i = 0; i < 4; i++)
#pragma unroll
          for (int j = 0; j < 4; j++) cf[i][j] = fmaf(av[i], bv[j], cf[i][j]);
      }
#pragma unroll
      for (int i = 0; i < 4; i++)
#pragma unroll
        for (int j = 0; j < 4; j++) acc[i][j] += (double)cf[i][j];
      __syncthreads();
    }
#pragma unroll
    for (int i = 0; i < 4; i++) {
      int gi = i0 + ty * 4 + i;
#pragma unroll
      for (int j = 0; j < 4; j++) {
        int gj = j0 + tx * 4 + j;
        float o = (float)acc[i][j];
        unsigned short l0, l1, l2;
        split3_1(o, l0, l1, l2);
        size_t idx = (size_t)gi * 512 + gj;
        Wcs[idx] = l0; Wcs[idx + 262144] = l1; Wcs[idx + 524288] = l2;
      }
    }
    return;
  }

  if (b < 1472) {  // ---- zero Vt pad: 128 z x 64 d x 28 kk = 229376 ----
    long long p0 = (long long)(b - 1360) * 2048 + tid * 8;
#pragma unroll
    for (int e = 0; e < 8; e++) {
      long long pf = p0 + e;
      int z = (int)(pf / 1792);
      int r = (int)(pf - (long long)z * 1792);
      int d = r / 28, kk = r - d * 28;
      Vt[(size_t)z * 14336 + (size_t)d * 224 + 196 + kk] = 0.0f;
    }
    return;
  }

  if (b == 1472) {  // ---- bcomb ----
#pragma unroll
    for (int half = 0; half < 2; half++) {
      int n = tid + half * 256;
      const float* wr = W1 + (size_t)n * 512;
      double acc = 0.0;
      for (int k = 0; k < 512; k += 4) {
        float4 wv = *(const float4*)&wr[k];
        float4 bv = *(const float4*)&bo[k];
        acc += (double)wv.x * bv.x + (double)wv.y * bv.y +
               (double)wv.z * bv.z + (double)wv.w * bv.w;
      }
      bcomb[n] = (float)(acc + (double)b1[n]);
    }
    return;
  }

  // b == 1473: biasAll
#pragma unroll
  for (int e = 0; e < 8; e++) {
    int idx = tid * 8 + e;
    biasAll[idx] = (idx < 1536) ? bqkv[idx] : 0.0f;
  }
}

#define GBK 32
#define AROWB 80                 // LDS bytes per row (32 bf16 + 16B pad)
#define SPLIT_SZ (128 * AROWB)   // 10240 B per limb plane
#define BBASE (3 * SPLIT_SZ)     // B tile base: 30720

// ---------------------------------------------------------------------------
// Pre-split bf16x3 MFMA GEMM. As/Bs: 3-plane bf16 limb tensors (row stride
// 512, plane strides aPlane/bPlane). N%128==0; M guarded. Split-K via
// blockIdx.z: kOff = z*kLen, C += z*cZStride; bias/res only on z==0.
// Optional VtOut: cols [1024,1536) are written transposed into
// Vt[z=(row/196)*8+(d>>6)][d&63][kk=row%196] instead of C.
// ---------------------------------------------------------------------------
__global__ __launch_bounds__(256) void gemm_ps3_kernel(
    const unsigned short* __restrict__ As, const unsigned short* __restrict__ Bs,
    float* __restrict__ C, const float* __restrict__ bias,
    const float* __restrict__ res,
    int M, int N, int ldc, int ldres,
    long long aPlane, long long bPlane,
    int kLen, long long cZStride,
    float* __restrict__ VtOut)
{
  __shared__ __align__(16) unsigned char smem[2 * BBASE];  // 61440 B

  int z = blockIdx.z;
  int kOff = z * kLen;
  C += (size_t)z * cZStride;

  int tid = threadIdx.x;
  int lane = tid & 63, w = tid >> 6;
  int wrow = w >> 1, wcol = w & 1;
  int i0 = blockIdx.x * 128, j0 = blockIdx.y * 128;

  int r = tid >> 1, hh = tid & 1;
  int arow = i0 + r; if (arow > M - 1) arow = M - 1;
  int brow = j0 + r; if (brow > N - 1) brow = N - 1;
  const unsigned short* ap = As + (size_t)arow * 512 + hh * 16 + kOff;
  const unsigned short* bp = Bs + (size_t)brow * 512 + hh * 16 + kOff;
  unsigned swoff = (unsigned)r * AROWB + (unsigned)hh * 32;

  f32x4v acc[4][4];
#pragma unroll
  for (int fi = 0; fi < 4; fi++)
#pragma unroll
    for (int fj = 0; fj < 4; fj++) acc[fi][fj] = (f32x4v){0.f, 0.f, 0.f, 0.f};

  unsigned fr_a = (unsigned)(wrow * 64 + (lane & 15)) * AROWB + (unsigned)(lane >> 4) * 16;
  unsigned fr_b = (unsigned)(wcol * 64 + (lane & 15)) * AROWB + (unsigned)(lane >> 4) * 16 + BBASE;

  for (int k0 = 0; k0 < kLen; k0 += GBK) {
    bf16x8v a0[3], a1[3], b0v[3], b1v[3];
#pragma unroll
    for (int s = 0; s < 3; s++) {
      a0[s]  = *(const bf16x8v*)(ap + s * aPlane + k0);
      a1[s]  = *(const bf16x8v*)(ap + s * aPlane + k0 + 8);
      b0v[s] = *(const bf16x8v*)(bp + s * bPlane + k0);
      b1v[s] = *(const bf16x8v*)(bp + s * bPlane + k0 + 8);
    }
    __syncthreads();  // previous chunk's frag reads complete
#pragma unroll
    for (int s = 0; s < 3; s++) {
      *(bf16x8v*)(smem + s * SPLIT_SZ + swoff)              = a0[s];
      *(bf16x8v*)(smem + s * SPLIT_SZ + swoff + 16)         = a1[s];
      *(bf16x8v*)(smem + BBASE + s * SPLIT_SZ + swoff)      = b0v[s];
      *(bf16x8v*)(smem + BBASE + s * SPLIT_SZ + swoff + 16) = b1v[s];
    }
    __syncthreads();

    bf16x8v af[4][3];
#pragma unroll
    for (int fi = 0; fi < 4; fi++)
#pragma unroll
      for (int s = 0; s < 3; s++)
        af[fi][s] = *(const bf16x8v*)(smem + s * SPLIT_SZ + fr_a + fi * (16 * AROWB));

#pragma unroll
    for (int fj = 0; fj < 4; fj++) {
      bf16x8v b0 = *(const bf16x8v*)(smem + 0 * SPLIT_SZ + fr_b + fj * (16 * AROWB));
      bf16x8v b1 = *(const bf16x8v*)(smem + 1 * SPLIT_SZ + fr_b + fj * (16 * AROWB));
      bf16x8v b2 = *(const bf16x8v*)(smem + 2 * SPLIT_SZ + fr_b + fj * (16 * AROWB));
#pragma unroll
      for (int fi = 0; fi < 4; fi++) {
        f32x4v c = acc[fi][fj];
        c = __builtin_amdgcn_mfma_f32_16x16x32_bf16(af[fi][2], b0, c, 0, 0, 0);
        c = __builtin_amdgcn_mfma_f32_16x16x32_bf16(af[fi][1], b1, c, 0, 0, 0);
        c = __builtin_amdgcn_mfma_f32_16x16x32_bf16(af[fi][0], b2, c, 0, 0, 0);
        c = __builtin_amdgcn_mfma_f32_16x16x32_bf16(af[fi][1], b0, c, 0, 0, 0);
        c = __builtin_amdgcn_mfma_f32_16x16x32_bf16(af[fi][0], b1, c, 0, 0, 0);
        c = __builtin_amdgcn_mfma_f32_16x16x32_bf16(af[fi][0], b0, c, 0, 0, 0);
        acc[fi][fj] = c;
      }
    }
  }

#pragma unroll
  for (int fi = 0; fi < 4; fi++) {
    int row0 = i0 + wrow * 64 + fi * 16 + (lane >> 4) * 4;
#pragma unroll
    for (int fj = 0; fj < 4; fj++) {
      int col = j0 + wcol * 64 + fj * 16 + (lane & 15);
      if (col >= N) continue;
      float badd = (bias && z == 0) ? bias[col] : 0.0f;
      f32x4v v = acc[fi][fj];
#pragma unroll
      for (int rr = 0; rr < 4; rr++) {
        int row = row0 + rr;
        if (row < M) {
          float o = v[rr] + badd;
          if (res && z == 0) o += res[(size_t)row * ldres + col];
          if (VtOut && col >= 1024 && col < 1536) {
            int d = col - 1024;
            int bb = row / 196;
            int kk = row - bb * 196;
            int zz = bb * 8 + (d >> 6);
            VtOut[(size_t)zz * 14336 + (size_t)(d & 63) * 224 + kk] = o;
          } else {
            C[(size_t)row * ldc + col] = o;
          }
        }
      }
    }
  }
}

// ---------------------------------------------------------------------------
// On-the-fly bf16x3 MFMA GEMM (batched attention GEMMs: strided A/B with
// z-batching, K over-read tolerated). Optional limb output.
// ---------------------------------------------------------------------------
__global__ __launch_bounds__(256) void gemm_bf16x3_kernel(
    const float* __restrict__ A, const float* __restrict__ B,
    float* __restrict__ C, const float* __restrict__ bias,
    const float* __restrict__ res,
    int M, int N, int K, int lda, int ldb, int ldc,
    int zInner, long long aOuter, long long aInner,
    long long bOuter, long long bInner,
    long long cOuter, long long cInner,
    unsigned short* __restrict__ Cl, long long clPlane)
{
  int z = blockIdx.z;
  int zo = z / zInner, zi = z % zInner;
  A += zo * aOuter + zi * aInner;
  B += zo * bOuter + zi * bInner;
  long long coff = zo * cOuter + zi * cInner;
  if (C) C += coff;
  if (Cl) Cl += coff;

  __shared__ __align__(16) unsigned char smem[2 * BBASE];  // 61440 B

  int tid = threadIdx.x;
  int lane = tid & 63, w = tid >> 6;
  int wrow = w >> 1, wcol = w & 1;
  int i0 = blockIdx.x * 128, j0 = blockIdx.y * 128;

  int srow = tid >> 1;
  int skh  = tid & 1;
  int arow = i0 + srow; if (arow > M - 1) arow = M - 1;
  int brow = j0 + srow; if (brow > N - 1) brow = N - 1;
  const float* aptr = A + (size_t)arow * lda + skh * 16;
  const float* bptr = B + (size_t)brow * ldb + skh * 16;
  unsigned swoff = (unsigned)srow * AROWB + (unsigned)skh * 32;

  f32x4v acc[4][4];
#pragma unroll
  for (int fi = 0; fi < 4; fi++)
#pragma unroll
    for (int fj = 0; fj < 4; fj++) acc[fi][fj] = (f32x4v){0.f, 0.f, 0.f, 0.f};

  unsigned fr_a = (unsigned)(wrow * 64 + (lane & 15)) * AROWB + (unsigned)(lane >> 4) * 16;
  unsigned fr_b = (unsigned)(wcol * 64 + (lane & 15)) * AROWB + (unsigned)(lane >> 4) * 16 + BBASE;

  for (int k0 = 0; k0 < K; k0 += GBK) {
    float av[16], bv[16];
    {
      const float4 q0 = *(const float4*)(aptr + k0);
      const float4 q1 = *(const float4*)(aptr + k0 + 4);
      const float4 q2 = *(const float4*)(aptr + k0 + 8);
      const float4 q3 = *(const float4*)(aptr + k0 + 12);
      av[0]=q0.x; av[1]=q0.y; av[2]=q0.z; av[3]=q0.w;
      av[4]=q1.x; av[5]=q1.y; av[6]=q1.z; av[7]=q1.w;
      av[8]=q2.x; av[9]=q2.y; av[10]=q2.z; av[11]=q2.w;
      av[12]=q3.x; av[13]=q3.y; av[14]=q3.z; av[15]=q3.w;
      const float4 r0 = *(const float4*)(bptr + k0);
      const float4 r1 = *(const float4*)(bptr + k0 + 4);
      const float4 r2 = *(const float4*)(bptr + k0 + 8);
      const float4 r3 = *(const float4*)(bptr + k0 + 12);
      bv[0]=r0.x; bv[1]=r0.y; bv[2]=r0.z; bv[3]=r0.w;
      bv[4]=r1.x; bv[5]=r1.y; bv[6]=r1.z; bv[7]=r1.w;
      bv[8]=r2.x; bv[9]=r2.y; bv[10]=r2.z; bv[11]=r2.w;
      bv[12]=r3.x; bv[13]=r3.y; bv[14]=r3.z; bv[15]=r3.w;
    }
    unsigned short ha[3][16], hb[3][16];
#pragma unroll
    for (int e = 0; e < 16; e++) {
      split3_1(av[e], ha[0][e], ha[1][e], ha[2][e]);
      split3_1(bv[e], hb[0][e], hb[1][e], hb[2][e]);
    }
    __syncthreads();
#pragma unroll
    for (int s = 0; s < 3; s++) {
      bf16x8v v0, v1, w0, w1;
#pragma unroll
      for (int e = 0; e < 8; e++) {
        v0[e] = (short)ha[s][e]; v1[e] = (short)ha[s][8 + e];
        w0[e] = (short)hb[s][e]; w1[e] = (short)hb[s][8 + e];
      }
      *(bf16x8v*)(smem + s * SPLIT_SZ + swoff)              = v0;
      *(bf16x8v*)(smem + s * SPLIT_SZ + swoff + 16)         = v1;
      *(bf16x8v*)(smem + BBASE + s * SPLIT_SZ + swoff)      = w0;
      *(bf16x8v*)(smem + BBASE + s * SPLIT_SZ + swoff + 16) = w1;
    }
    __syncthreads();

    bf16x8v af[4][3];
#pragma unroll
    for (int fi = 0; fi < 4; fi++)
#pragma unroll
      for (int s = 0; s < 3; s++)
        af[fi][s] = *(const bf16x8v*)(smem + s * SPLIT_SZ + fr_a + fi * (16 * AROWB));

#pragma unroll
    for (int fj = 0; fj < 4; fj++) {
      bf16x8v b0 = *(const bf16x8v*)(smem + 0 * SPLIT_SZ + fr_b + fj * (16 * AROWB));
      bf16x8v b1 = *(const bf16x8v*)(smem + 1 * SPLIT_SZ + fr_b + fj * (16 * AROWB));
      bf16x8v b2 = *(const bf16x8v*)(smem + 2 * SPLIT_SZ + fr_b + fj * (16 * AROWB));
#pragma unroll
      for (int fi = 0; fi < 4; fi++) {
        f32x4v c = acc[fi][fj];
        c = __builtin_amdgcn_mfma_f32_16x16x32_bf16(af[fi][2], b0, c, 0, 0, 0);
        c = __builtin_amdgcn_mfma_f32_16x16x32_bf16(af[fi][1], b1, c, 0, 0, 0);
        c = __builtin_amdgcn_mfma_f32_16x16x32_bf16(af[fi][0], b2, c, 0, 0, 0);
        c = __builtin_amdgcn_mfma_f32_16x16x32_bf16(af[fi][1], b0, c, 0, 0, 0);
        c = __builtin_amdgcn_mfma_f32_16x16x32_bf16(af[fi][0], b1, c, 0, 0, 0);
        c = __builtin_amdgcn_mfma_f32_16x16x32_bf16(af[fi][0], b0, c, 0, 0, 0);
        acc[fi][fj] = c;
      }
    }
  }

#pragma unroll
  for (int fi = 0; fi < 4; fi++) {
    int row0 = i0 + wrow * 64 + fi * 16 + (lane >> 4) * 4;
#pragma unroll
    for (int fj = 0; fj < 4; fj++) {
      int col = j0 + wcol * 64 + fj * 16 + (lane & 15);
      if (col >= N) continue;
      float badd = bias ? bias[col] : 0.0f;
      f32x4v v = acc[fi][fj];
#pragma unroll
      for (int rr = 0; rr < 4; rr++) {
        int row = row0 + rr;
        if (row < M) {
          float o = v[rr] + badd;
          if (res) o += res[(size_t)row * ldc + col];
          size_t idx = (size_t)row * ldc + col;
          if (Cl) {
            unsigned short l0, l1, l2;
            split3_1(o, l0, l1, l2);
            Cl[idx] = l0; Cl[idx + clPlane] = l1; Cl[idx + 2 * clPlane] = l2;
          } else {
            C[idx] = o;
          }
        }
      }
    }
  }
}

// In-place row softmax of scaled scores: rows of length 196, scale 1/sqrt(64).
__global__ __launch_bounds__(256) void softmax_kernel(float* __restrict__ S)
{
  int row = blockIdx.x * 4 + (threadIdx.x >> 6);
  int lane = threadIdx.x & 63;
  float* sr = S + (size_t)row * 196;
  double v[4];
#pragma unroll
  for (int t = 0; t < 4; t++) {
    int j = lane + 64 * t;
    v[t] = (j < 196) ? (double)sr[j] * 0.125 : -1e300;
  }
  double mx = fmax(fmax(v[0], v[1]), fmax(v[2], v[3]));
#pragma unroll
  for (int off = 1; off < 64; off <<= 1) mx = fmax(mx, __shfl_xor(mx, off));
  double e[4]; double s = 0.0;
#pragma unroll
  for (int t = 0; t < 4; t++) {
    int j = lane + 64 * t;
    e[t] = (j < 196) ? exp(v[t] - mx) : 0.0;
    s += e[t];
  }
#pragma unroll
  for (int off = 1; off < 64; off <<= 1) s += __shfl_xor(s, off);
  double inv = 1.0 / s;
#pragma unroll
  for (int t = 0; t < 4; t++) {
    int j = lane + 64 * t;
    if (j < 196) sr[j] = (float)(e[t] * inv);
  }
}

// ---------------------------------------------------------------------------
// Fused LayerNorm (ddof=0, eps=1e-5) + exact GELU + w2 projection.
// h1 arrives as 4 split-K partials (fp64-summed here).
// ---------------------------------------------------------------------------
__global__ __launch_bounds__(256) void lnw2_kernel(
    const float* __restrict__ H, const float* __restrict__ g,
    const float* __restrict__ bb, const float* __restrict__ W2,
    const float* __restrict__ B2, float* __restrict__ Qp)
{
  int row = blockIdx.x;
  const float* hr = H + (size_t)row * 512;
  int tid = threadIdx.x, lane = tid & 63, wv = tid >> 6;
  __shared__ double red[8];
  __shared__ float y[512];
  double x0 = (double)hr[tid]       + (double)hr[tid + 1605632]
            + (double)hr[tid + 3211264] + (double)hr[tid + 4816896];
  double x1 = (double)hr[tid + 256] + (double)hr[tid + 256 + 1605632]
            + (double)hr[tid + 256 + 3211264] + (double)hr[tid + 256 + 4816896];
  double s = x0 + x1;
#pragma unroll
  for (int off = 1; off < 64; off <<= 1) s += __shfl_xor(s, off);
  if (lane == 0) red[wv] = s;
  __syncthreads();
  double mu = (red[0] + red[1] + red[2] + red[3]) * (1.0 / 512.0);
  double d0 = x0 - mu, d1 = x1 - mu;
  double q = d0 * d0 + d1 * d1;
#pragma unroll
  for (int off = 1; off < 64; off <<= 1) q += __shfl_xor(q, off);
  if (lane == 0) red[4 + wv] = q;
  __syncthreads();
  double var = (red[4] + red[5] + red[6] + red[7]) * (1.0 / 512.0);
  double inv = 1.0 / sqrt(var + 1e-5);
  double y0 = d0 * inv * (double)g[tid]       + (double)bb[tid];
  double y1 = d1 * inv * (double)g[tid + 256] + (double)bb[tid + 256];
  const double ISQRT2 = 0.70710678118654752440;
  double z0 = 0.5 * y0 * (1.0 + erf(y0 * ISQRT2));
  double z1 = 0.5 * y1 * (1.0 + erf(y1 * ISQRT2));
  y[tid] = (float)z0;
  y[tid + 256] = (float)z1;
  __syncthreads();

#pragma unroll 1
  for (int t = 0; t < 5; t++) {
    int m = wv * 5 + t;
    const float* wr = W2 + (size_t)m * 512;
    double acc = 0.0;
#pragma unroll
    for (int sE = 0; sE < 8; sE++) {
      int j = lane + 64 * sE;
      acc += (double)y[j] * (double)wr[j];
    }
#pragma unroll
    for (int off = 1; off < 64; off <<= 1) acc += __shfl_xor(acc, off);
    if (lane == 0) Qp[(size_t)row * 20 + m] = (float)(acc + (double)B2[m]);
  }
}

// ---------------------------------------------------------------------------
// topk selection v5: two tasks/wave, guarded ballots, 32-bit prefix search,
// min/max seeding, early exit; prefix-tie boundary resolved exactly by
// (low-32 desc, d asc). fp32 finish. Emits 8 ballot words + qif per (bn,m).
// ---------------------------------------------------------------------------
__device__ __forceinline__ void topk_finish32(
    const unsigned* uh, const unsigned* ul, const float* apf,
    unsigned thrh, bool exact, float qp, int g,
    unsigned long long* __restrict__ masks, float* __restrict__ qif, int lane)
{
  const int KSEL = 51;
  bool sel[8];
  if (exact) {
#pragma unroll
    for (int s = 0; s < 8; s++) sel[s] = (uh[s] >= thrh);
  } else {
    int cg = 0;
#pragma unroll
    for (int s = 0; s < 8; s++) {
      sel[s] = (uh[s] > thrh);
      cg += (int)__popcll(__ballot(sel[s]));
    }
    int need = KSEL - cg;
    bool tk[8];
#pragma unroll
    for (int s = 0; s < 8; s++) tk[s] = false;
    while (need > 0) {
      unsigned long long bk = 0ULL;
#pragma unroll
      for (int s = 0; s < 8; s++) {
        if (uh[s] == thrh && !tk[s]) {
          unsigned long long key = (1ULL << 41)
                                 | ((unsigned long long)ul[s] << 9)
                                 | ((unsigned long long)(7 - s) << 6)
                                 | (unsigned long long)(63 - lane);
          bk = key > bk ? key : bk;
        }
      }
#pragma unroll
      for (int off = 1; off < 64; off <<= 1) {
        unsigned long long ob = __shfl_xor(bk, off);
        bk = ob > bk ? ob : bk;
      }
      if ((int)(63 - (bk & 63ULL)) == lane) {
        int wsI = 7 - (int)((bk >> 6) & 7ULL);
        sel[wsI] = true;
        tk[wsI] = true;
      }
      need--;
    }
  }

  float ss = 0.f;
  unsigned long long selb[8];
#pragma unroll
  for (int s = 0; s < 8; s++) {
    selb[s] = __ballot((int)sel[s]);
    if (sel[s]) ss += apf[s] * apf[s];
  }
#pragma unroll
  for (int off = 1; off < 64; off <<= 1) ss += __shfl_xor(ss, off);
  float nrm = fabsf(qp) * sqrtf(ss);
  float qid = qp / fmaxf(nrm, 1e-6f);
  if (lane == 0) {
    qif[g] = qid;
#pragma unroll
    for (int s = 0; s < 8; s++) masks[(size_t)g * 8 + s] = selb[s];
  }
}

__global__ __launch_bounds__(256) void topk_select_kernel(
    const float* __restrict__ F, const float* __restrict__ T,
    const float* __restrict__ Qp, unsigned long long* __restrict__ masks,
    float* __restrict__ qif)
{
  const int KSEL = 51;
  int wid = blockIdx.x * 4 + (threadIdx.x >> 6);
  int lane = threadIdx.x & 63;
  int g0 = wid * 2;                 // two tasks, same bn (20 % 2 == 0)
  int bn = g0 / 20, m0 = g0 - bn * 20;
  const float* Frow = F + (size_t)bn * 512;
  const float* T0r = T + (size_t)m0 * 512;
  const float* T1r = T0r + 512;

  unsigned uh0[8], ul0[8], uh1[8], ul1[8];
  float ap0[8], ap1[8];
#pragma unroll
  for (int s = 0; s < 8; s++) {
    double fd = (double)Frow[lane + 64 * s];
    double p0 = fd * (double)T0r[lane + 64 * s];   // exact in fp64
    double p1 = fd * (double)T1r[lane + 64 * s];
    unsigned long long u0 =
        (unsigned long long)__double_as_longlong(p0) & 0x7fffffffffffffffULL;
    unsigned long long u1 =
        (unsigned long long)__double_as_longlong(p1) & 0x7fffffffffffffffULL;
    uh0[s] = (unsigned)(u0 >> 32); ul0[s] = (unsigned)u0;
    uh1[s] = (unsigned)(u1 >> 32); ul1[s] = (unsigned)u1;
    ap0[s] = (float)fabs(p0); ap1[s] = (float)fabs(p1);
  }

  unsigned mx0 = 0u, mn0 = 0xffffffffu, mx1 = 0u, mn1 = 0xffffffffu;
#pragma unroll
  for (int s = 0; s < 8; s++) {
    mx0 = uh0[s] > mx0 ? uh0[s] : mx0;  mn0 = uh0[s] < mn0 ? uh0[s] : mn0;
    mx1 = uh1[s] > mx1 ? uh1[s] : mx1;  mn1 = uh1[s] < mn1 ? uh1[s] : mn1;
  }
#pragma unroll
  for (int off = 1; off < 64; off <<= 1) {
    unsigned a = __shfl_xor(mx0, off); mx0 = a > mx0 ? a : mx0;
    unsigned b = __shfl_xor(mn0, off); mn0 = b < mn0 ? b : mn0;
    unsigned c = __shfl_xor(mx1, off); mx1 = c > mx1 ? c : mx1;
    unsigned d = __shfl_xor(mn1, off); mn1 = d < mn1 ? d : mn1;
  }

  unsigned lo0 = mn0, hi0 = mx0 + 1u, lo1 = mn1, hi1 = mx1 + 1u;
  bool ex0 = false, ex1 = false;
  bool dn0 = (hi0 - lo0 <= 1u), dn1 = (hi1 - lo1 <= 1u);
  while (!(dn0 && dn1)) {
    if (!dn0) {   // wave-uniform guard
      unsigned mid = lo0 + ((hi0 - lo0) >> 1);
      int c = 0;
#pragma unroll
      for (int s = 0; s < 8; s++) c += (int)__popcll(__ballot(uh0[s] >= mid));
      if (c >= KSEL) { lo0 = mid; if (c == KSEL) { ex0 = true; dn0 = true; } }
      else hi0 = mid;
      dn0 = dn0 || (hi0 - lo0 <= 1u);
    }
    if (!dn1) {
      unsigned mid = lo1 + ((hi1 - lo1) >> 1);
      int c = 0;
#pragma unroll
      for (int s = 0; s < 8; s++) c += (int)__popcll(__ballot(uh1[s] >= mid));
      if (c >= KSEL) { lo1 = mid; if (c == KSEL) { ex1 = true; dn1 = true; } }
      else hi1 = mid;
      dn1 = dn1 || (hi1 - lo1 <= 1u);
    }
  }
  topk_finish32(uh0, ul0, ap0, lo0, ex0, Qp[g0],     g0,     masks, qif, lane);
  topk_finish32(uh1, ul1, ap1, lo1, ex1, Qp[g0 + 1], g0 + 1, masks, qif, lane);
}

// ---------------------------------------------------------------------------
// topk writeout: LDS value tile (two 256-d halves) -> fully coalesced
// contiguous float4 stores.
// ---------------------------------------------------------------------------
__global__ __launch_bounds__(256) void topk_write_kernel(
    const float* __restrict__ F, const float* __restrict__ T,
    const unsigned long long* __restrict__ masks,
    const float* __restrict__ qif, float* __restrict__ out)
{
  int bn = blockIdx.x;
  int tid = threadIdx.x;
  __shared__ unsigned long long mw[20][8];
  __shared__ float qf[20];
  __shared__ float vt[256][21];   // [d_local][m], stride 21: conflict-free
  if (tid < 160) ((unsigned long long*)mw)[tid] = masks[(size_t)bn * 160 + tid];
  if (tid < 20) qf[tid] = qif[(size_t)bn * 20 + tid];
  const float* Frow = F + (size_t)bn * 512;
  float* orow = out + (size_t)bn * 10240;
  __syncthreads();

#pragma unroll
  for (int half = 0; half < 2; half++) {
    int d = half * 256 + tid;
    float fd = Frow[d];
    int dw = d >> 6, db = d & 63;
#pragma unroll
    for (int m = 0; m < 20; m++) {
      bool sel = (mw[m][dw] >> db) & 1ULL;
      float tv = T[(size_t)m * 512 + d];
      vt[tid][m] = sel ? fd * tv * qf[m] : 0.0f;
    }
    __syncthreads();
#pragma unroll
    for (int k = 0; k < 5; k++) {
      int flat = (k * 256 + tid) * 4;     // element within half [0,5120)
      float v[4];
#pragma unroll
      for (int e = 0; e < 4; e++) {
        int fe = flat + e;
        int dl = fe / 20;
        int mm = fe - dl * 20;
        v[e] = vt[dl][mm];
      }
      float4 o = {v[0], v[1], v[2], v[3]};
      *(float4*)&orow[half * 5120 + flat] = o;
    }
    __syncthreads();
  }
}

extern "C" void kernel_launch(void* const* d_in, const int* in_sizes, int n_in,
                              void* d_out, int out_size, void* d_ws, size_t ws_size,
                              hipStream_t stream) {
  const float* F    = (const float*)d_in[0];   // [3136,512]
  const float* Wqkv = (const float*)d_in[1];   // [1536,512]
  const float* bqkv = (const float*)d_in[2];   // [1536]
  const float* Wo   = (const float*)d_in[3];   // [512,512]
  const float* bo   = (const float*)d_in[4];   // [512]
  const float* W1   = (const float*)d_in[5];   // [512,512]
  const float* b1   = (const float*)d_in[6];   // [512]
  const float* lng  = (const float*)d_in[7];   // [512]
  const float* lnb  = (const float*)d_in[8];   // [512]
  const float* W2   = (const float*)d_in[9];   // [20,512]
  const float* b2   = (const float*)d_in[10];  // [20]
  const float* Tm   = (const float*)d_in[11];  // [20,512]
  float* out = (float*)d_out;

  float* ws = (float*)d_ws;
  // Dedicated regions (no overlays; ~110 MB total, fits d_ws):
  float* qkvw   = ws;                          // [3136,2048] = 6,422,528
  float* scores = ws + 6422528;                // 4,917,248
  float* Vt     = ws + 11339776;               // 128*64*224 = 1,835,008
  float* h1p    = ws + 13174784;               // 4 x 1,605,632 = 6,422,528
  float* Qp     = ws + 19597312;               //    62,720
  float* bcomb  = ws + 19660032;               //       512
  float* biasAll= ws + 19660544;               //     2,048
  unsigned long long* masks = (unsigned long long*)(ws + 19662592);  // 1,003,520 fl
  float* qifb   = ws + 20666112;               //    62,720
  unsigned short* Fs    = (unsigned short*)(ws + 20728832);  // 2,408,448 fl
  unsigned short* Walls = (unsigned short*)(ws + 23137280);  // 1,572,864 fl
  unsigned short* Wcs   = (unsigned short*)(ws + 24710144);  //   393,216 fl
  unsigned short* Omgs  = (unsigned short*)(ws + 25103360);  // 2,408,448 fl
  dim3 blk(256);

  // 1) prep: limb splits (F, Wqkv+W1 -> Walls), Wc = W1@Wo -> limbs,
  //    Vt pad zero, bcomb, biasAll
  prep_kernel<<<dim3(1474), blk, 0, stream>>>(
      F, Fs, Wqkv, W1, Walls, Wo, Wcs, Vt, bo, b1, bcomb, bqkv, biasAll);

  // 2) qkvw = F @ [Wqkv;W1]^T + biasAll      [3136,2048]  (pre-split MFMA)
  //    cols [0,1024): Q,K -> qkvw; [1024,1536): V -> Vt transposed;
  //    [1536,2048): F@W1^T -> qkvw (res for h1)
  gemm_ps3_kernel<<<dim3(25, 16, 1), blk, 0, stream>>>(
      Fs, Walls, qkvw, biasAll, nullptr,
      3136, 2048, 2048, 0, 1605632LL, 1048576LL, 512, 0LL, Vt);

  // 3) scores[b,h] = Q[b,h] @ K[b,h]^T       [196,196] x 128  (on-the-fly)
  gemm_bf16x3_kernel<<<dim3(2, 2, 128), blk, 0, stream>>>(
      qkvw, qkvw + 512, scores, nullptr, nullptr,
      196, 196, 64, 2048, 2048, 196,
      8, 196LL * 2048, 64, 196LL * 2048, 64, 8LL * 38416, 38416,
      nullptr, 0);

  // 4) softmax rows (scale 0.125 inside)
  softmax_kernel<<<dim3(6272), blk, 0, stream>>>(scores);

  // 5) O[b,h] = P[b,h] @ Vt[b,h]^T -> Omg LIMBS directly
  gemm_bf16x3_kernel<<<dim3(2, 1, 128), blk, 0, stream>>>(
      scores, Vt, nullptr, nullptr, nullptr,
      196, 64, 196, 196, 224, 512,
      8, 8LL * 38416, 38416, 8LL * 14336, 14336, 100352, 64,
      Omgs, 1605632LL);

  // 6) h1 = Omg @ Wc^T + FW1 + bcomb, split-K x4 -> 4 partials
  gemm_ps3_kernel<<<dim3(25, 4, 4), blk, 0, stream>>>(
      Omgs, Wcs, h1p, bcomb, qkvw + 1536,
      3136, 512, 512, 2048, 1605632LL, 262144LL, 128, 1605632LL, nullptr);

  // 7) fused LayerNorm + exact GELU + w2 -> Qp  (sums 4 partials)
  lnw2_kernel<<<dim3(3136), blk, 0, stream>>>(h1p, lng, lnb, W2, b2, Qp);

  // 8) selection: 2 tasks/wave, guarded ballots
  topk_select_kernel<<<dim3(7840), blk, 0, stream>>>(F, Tm, Qp, masks, qifb);

  // 9) streaming writeout of [B,N,D,M], coalesced via LDS tile
  topk_write_kernel<<<dim3(3136), blk, 0, stream>>>(F, Tm, masks, qifb, out);
}